// Round 1
// baseline (267.881 us; speedup 1.0000x reference)
//
#include <hip/hip_runtime.h>
#include <hip/hip_bf16.h>

// ROUND 11: attention register double-buffer — prefetch K/Vt tile kt+1 into a
// second register set while computing tile kt (ping-pong, no runtime-indexed
// arrays -> no scratch). Hides ~200-900cy global-load latency behind the
// ~400cy MFMA+exp2 compute phase; kernel stays barrier-free with per-wave
// loop bounds. GEMMs + transpose unchanged from R10.
// ws (bf16): q[4M] k[4M] v/ao[4M] vt[4M] = 32MB.

typedef __attribute__((ext_vector_type(8))) short bf16x8;
typedef __attribute__((ext_vector_type(4))) short bf16x4;
typedef __attribute__((ext_vector_type(4))) float floatx4;

#define MFMA16(a, b, c) __builtin_amdgcn_mfma_f32_16x16x32_bf16((a), (b), (c), 0, 0, 0)

#if __has_builtin(__builtin_amdgcn_exp2f)
#define EXP2F(x) __builtin_amdgcn_exp2f(x)
#else
#define EXP2F(x) exp2f(x)
#endif

static constexpr int Bc = 2, Tc = 2048, Cc = 1024, Hc = 16, Dc = 64;
static constexpr size_t QKV_STRIDE = (size_t)Bc * Hc * Tc * Dc; // 4194304
static constexpr float KSL2E = 0.125f * 1.44269504088896f; // scale * log2(e)

__device__ __forceinline__ bf16x8 load8(const __hip_bfloat16* p) {
    return *(const bf16x8*)p;
}

__device__ __forceinline__ bf16x8 load8_lds(const __hip_bfloat16* p) {
    const bf16x4 lo = *(const bf16x4*)p;
    const bf16x4 hi = *(const bf16x4*)(p + 4);
    bf16x8 r;
    r[0] = lo[0]; r[1] = lo[1]; r[2] = lo[2]; r[3] = lo[3];
    r[4] = hi[0]; r[5] = hi[1]; r[6] = hi[2]; r[7] = hi[3];
    return r;
}

__device__ __forceinline__ short f2b(float x) {
    union { __hip_bfloat16 h; short s; } u;
    u.h = __float2bfloat16(x);
    return u.s;
}

__device__ __forceinline__ bf16x8 pack8(floatx4 a, floatx4 b) {
    bf16x8 r;
    r[0] = f2b(a[0]); r[1] = f2b(a[1]); r[2] = f2b(a[2]); r[3] = f2b(a[3]);
    r[4] = f2b(b[0]); r[5] = f2b(b[1]); r[6] = f2b(b[2]); r[7] = f2b(b[3]);
    return r;
}

__device__ __forceinline__ void gl2lds16(const void* g, void* l) {
    __builtin_amdgcn_global_load_lds(
        (const __attribute__((address_space(1))) void*)g,
        (__attribute__((address_space(3))) void*)l, 16, 0, 0);
}

// ================= GEMM1 (unchanged): qkv = x @ w_qkv^T =====================
__global__ __launch_bounds__(256) void gemm_qkv(
    const float* __restrict__ A,
    const float* __restrict__ W,
    __hip_bfloat16* __restrict__ qkv) {
    __shared__ float As[128 * 32];
    __shared__ float Bs[128 * 32];
    const int K = Cc;
    const int lane = threadIdx.x & 63;
    const int wave = threadIdx.x >> 6;
    const int waveM = wave >> 1, waveN = wave & 1;
    const int mBase = blockIdx.x * 128;
    const int nBase = blockIdx.y * 128;
    const int idx16 = lane & 15;
    const int quad = lane >> 4;

    const int ldRow = lane >> 3;
    const int ldPos = lane & 7;

    floatx4 acc[4][4] = {};

    for (int k0 = 0; k0 < K; k0 += 32) {
        __syncthreads();
#pragma unroll
        for (int s = 0; s < 4; s++) {
            const int r0 = wave * 32 + s * 8;
            const int row = r0 + ldRow;
            const int cg = ldPos ^ (row & 7);
            gl2lds16(A + (size_t)(mBase + row) * K + k0 + cg * 4, &As[r0 * 32]);
            gl2lds16(W + (size_t)(nBase + row) * K + k0 + cg * 4, &Bs[r0 * 32]);
        }
        __syncthreads();

        bf16x8 af[4], bfr[4];
#pragma unroll
        for (int i = 0; i < 4; i++) {
            const int rr = waveM * 64 + i * 16 + idx16;
            const floatx4 a0 = *(const floatx4*)&As[rr * 32 + (((quad * 2) ^ (rr & 7)) * 4)];
            const floatx4 a1 = *(const floatx4*)&As[rr * 32 + (((quad * 2 + 1) ^ (rr & 7)) * 4)];
            af[i] = pack8(a0, a1);
        }
#pragma unroll
        for (int j = 0; j < 4; j++) {
            const int rr = waveN * 64 + j * 16 + idx16;
            const floatx4 b0 = *(const floatx4*)&Bs[rr * 32 + (((quad * 2) ^ (rr & 7)) * 4)];
            const floatx4 b1 = *(const floatx4*)&Bs[rr * 32 + (((quad * 2 + 1) ^ (rr & 7)) * 4)];
            bfr[j] = pack8(b0, b1);
        }
#pragma unroll
        for (int i = 0; i < 4; i++)
#pragma unroll
            for (int j = 0; j < 4; j++)
                acc[i][j] = MFMA16(af[i], bfr[j], acc[i][j]);
    }

#pragma unroll
    for (int i = 0; i < 4; i++) {
#pragma unroll
        for (int j = 0; j < 4; j++) {
            const int n = nBase + waveN * 64 + j * 16 + idx16;
            const int part = n >> 10;
            const int rem = n & 1023;
            const int h = rem >> 6, d = rem & 63;
#pragma unroll
            for (int r = 0; r < 4; r++) {
                const int m = mBase + waveM * 64 + i * 16 + quad * 4 + r;
                const int bb = m >> 11, t = m & 2047;
                const size_t o = (size_t)part * QKV_STRIDE +
                                 (((size_t)(bb * Hc + h)) * Tc + t) * Dc + d;
                qkv[o] = __float2bfloat16(acc[i][j][r]);
            }
        }
    }
}

// ================= GEMM2 (unchanged): out(f32) = ao @ w_proj^T ==============
__global__ __launch_bounds__(256) void gemm_proj(
    const __hip_bfloat16* __restrict__ A,
    const float* __restrict__ W,
    float* __restrict__ out) {
    __shared__ __hip_bfloat16 As16[128 * 32];
    __shared__ float Ws[64 * 32];
    const int K = Cc;
    const int lane = threadIdx.x & 63;
    const int wave = threadIdx.x >> 6;
    const int waveM = wave >> 1, waveN = wave & 1;
    const int mBase = blockIdx.x * 128;
    const int nBase = blockIdx.y * 64;
    const int idx16 = lane & 15;
    const int quad = lane >> 4;

    const int aRow = lane >> 2, aPos = lane & 3;
    const int wRow = lane >> 3, wPos = lane & 7;

    floatx4 acc[4][2] = {};

    for (int k0 = 0; k0 < K; k0 += 32) {
        __syncthreads();
#pragma unroll
        for (int s = 0; s < 2; s++) {
            {
                const int r0 = wave * 32 + s * 16;
                const int row = r0 + aRow;
                const int cg = aPos ^ (row & 3);
                gl2lds16(A + (size_t)(mBase + row) * K + k0 + cg * 8, &As16[r0 * 32]);
            }
            {
                const int r0 = wave * 16 + s * 8;
                const int row = r0 + wRow;
                const int cg = wPos ^ (row & 7);
                gl2lds16(W + (size_t)(nBase + row) * K + k0 + cg * 4, &Ws[r0 * 32]);
            }
        }
        __syncthreads();

        bf16x8 af[4], bfr[2];
#pragma unroll
        for (int i = 0; i < 4; i++) {
            const int rr = waveM * 64 + i * 16 + idx16;
            af[i] = *(const bf16x8*)&As16[rr * 32 + ((quad ^ (rr & 3)) * 8)];
        }
#pragma unroll
        for (int j = 0; j < 2; j++) {
            const int rr = waveN * 32 + j * 16 + idx16;
            const floatx4 b0 = *(const floatx4*)&Ws[rr * 32 + (((quad * 2) ^ (rr & 7)) * 4)];
            const floatx4 b1 = *(const floatx4*)&Ws[rr * 32 + (((quad * 2 + 1) ^ (rr & 7)) * 4)];
            bfr[j] = pack8(b0, b1);
        }
#pragma unroll
        for (int i = 0; i < 4; i++)
#pragma unroll
            for (int j = 0; j < 2; j++)
                acc[i][j] = MFMA16(af[i], bfr[j], acc[i][j]);
    }

#pragma unroll
    for (int i = 0; i < 4; i++) {
#pragma unroll
        for (int j = 0; j < 2; j++) {
            const int n = nBase + waveN * 32 + j * 16 + idx16;
#pragma unroll
            for (int r = 0; r < 4; r++) {
                const int m = mBase + waveM * 64 + i * 16 + quad * 4 + r;
                out[(size_t)m * Cc + n] = acc[i][j][r];
            }
        }
    }
}

// ================= V transpose (unchanged): [b,h,t,d] -> [b,h,d,t] ==========
__global__ __launch_bounds__(256) void transpose_v(
    const __hip_bfloat16* __restrict__ v,
    __hip_bfloat16* __restrict__ vt) {
    __shared__ unsigned short tile[64][65];
    const int t0 = blockIdx.x * 64;
    const int h = blockIdx.y, b = blockIdx.z;
    const size_t base = ((size_t)(b * Hc + h)) * Tc * Dc;
    const unsigned short* vp = (const unsigned short*)v + base;
    unsigned short* vtp = (unsigned short*)vt + base;

    for (int e = threadIdx.x; e < 4096; e += 256) {
        const int tl = e >> 6, d = e & 63;
        tile[tl][d] = vp[(size_t)(t0 + tl) * Dc + d];
    }
    __syncthreads();
    for (int e = threadIdx.x; e < 4096; e += 256) {
        const int d = e >> 6, tl = e & 63;
        vtp[(size_t)d * Tc + t0 + tl] = tile[tl][d];
    }
}

// ================= Flash attention v4: register-double-buffered =============
// Block = 128 q (4 waves x 32 q) for one (b,h). Each wave: two 16-row A-frags
// sharing every K/Vt load. Tile kt+1's 16 global loads are issued into the
// alternate register set BEFORE computing tile kt, so L2/HBM latency hides
// under the MFMA+exp2 phase. Ping-pong with statically-named register sets
// (no runtime-indexed arrays -> no scratch). m=0 softmax, branchless mask,
// per-wave loop bound, no barriers.
__global__ __launch_bounds__(256) void attn_kernel(
    const __hip_bfloat16* __restrict__ qkv,
    const __hip_bfloat16* __restrict__ vt,
    __hip_bfloat16* __restrict__ aout) {
    __shared__ __hip_bfloat16 lds_p[4][2][16][72];  // per-wave x 2 frags

    const int lane = threadIdx.x & 63;
    const int wave = threadIdx.x >> 6;
    const int col = lane & 15;
    const int quad = lane >> 4;
    const int qt = (gridDim.x - 1) - blockIdx.x;    // heavy blocks first
    const int h = blockIdx.y;
    const int b = blockIdx.z;
    const int qBase = qt * 128;

    const size_t headOff = ((size_t)(b * Hc + h)) * Tc * Dc;
    const __hip_bfloat16* qp = qkv + headOff;
    const __hip_bfloat16* kp = qkv + QKV_STRIDE + headOff;
    const __hip_bfloat16* vtp = vt + headOff;       // [d][t] within head

    const int qrowA = qBase + wave * 32 + col;      // frag A rows
    const int qrowB = qrowA + 16;                   // frag B rows
    bf16x8 qfa[2], qfb[2];
    qfa[0] = load8(qp + (size_t)qrowA * Dc + quad * 8);
    qfa[1] = load8(qp + (size_t)qrowA * Dc + 32 + quad * 8);
    qfb[0] = load8(qp + (size_t)qrowB * Dc + quad * 8);
    qfb[1] = load8(qp + (size_t)qrowB * Dc + 32 + quad * 8);

    floatx4 oa[4] = {}, ob[4] = {};
    float la[4] = {0.f, 0.f, 0.f, 0.f}, lb[4] = {0.f, 0.f, 0.f, 0.f};
    const int q0a = qBase + wave * 32 + quad * 4;
    const int q0b = q0a + 16;
    const int qtw = (qBase + wave * 32 + 31) >> 6;  // last K-tile for this wave

    // --- tile load: 8 K-frags + 8 Vt-frags into a named register set ---
    auto tload = [&](int kt, bf16x8* k0, bf16x8* k1, bf16x8* v0, bf16x8* v1) {
        const int keyBase = kt * 64;
#pragma unroll
        for (int j = 0; j < 4; j++) {
            const int key = keyBase + j * 16 + col;
            k0[j] = load8(kp + (size_t)key * Dc + quad * 8);
            k1[j] = load8(kp + (size_t)key * Dc + 32 + quad * 8);
        }
#pragma unroll
        for (int j = 0; j < 4; j++) {
            const int d = j * 16 + col;
            v0[j] = load8(vtp + (size_t)d * Tc + keyBase + quad * 8);
            v1[j] = load8(vtp + (size_t)d * Tc + keyBase + 32 + quad * 8);
        }
    };

    // --- tile compute: QK^T -> exp2+mask -> P via LDS -> O += P V ---
    auto tcompute = [&](int kt, const bf16x8* kc0, const bf16x8* kc1,
                        const bf16x8* vc0, const bf16x8* vc1) {
        const int keyBase = kt * 64;
        floatx4 sa[4], sb[4];
#pragma unroll
        for (int j = 0; j < 4; j++) {
            floatx4 a0 = {0.f, 0.f, 0.f, 0.f};
            a0 = MFMA16(qfa[0], kc0[j], a0);
            sa[j] = MFMA16(qfa[1], kc1[j], a0);
            floatx4 b0 = {0.f, 0.f, 0.f, 0.f};
            b0 = MFMA16(qfb[0], kc0[j], b0);
            sb[j] = MFMA16(qfb[1], kc1[j], b0);
        }

#pragma unroll
        for (int j = 0; j < 4; j++) {
            const int key = keyBase + j * 16 + col;
#pragma unroll
            for (int r = 0; r < 4; r++) {
                float pa = EXP2F(sa[j][r] * KSL2E);
                pa = (key > q0a + r) ? 0.f : pa;
                la[r] += pa;
                lds_p[wave][0][quad * 4 + r][j * 16 + col] = __float2bfloat16(pa);
                float pb = EXP2F(sb[j][r] * KSL2E);
                pb = (key > q0b + r) ? 0.f : pb;
                lb[r] += pb;
                lds_p[wave][1][quad * 4 + r][j * 16 + col] = __float2bfloat16(pb);
            }
        }

        const bf16x8 pa0 = load8_lds(&lds_p[wave][0][col][quad * 8]);
        const bf16x8 pa1 = load8_lds(&lds_p[wave][0][col][32 + quad * 8]);
        const bf16x8 pb0 = load8_lds(&lds_p[wave][1][col][quad * 8]);
        const bf16x8 pb1 = load8_lds(&lds_p[wave][1][col][32 + quad * 8]);
#pragma unroll
        for (int j = 0; j < 4; j++) {
            oa[j] = MFMA16(pa0, vc0[j], oa[j]);
            oa[j] = MFMA16(pa1, vc1[j], oa[j]);
            ob[j] = MFMA16(pb0, vc0[j], ob[j]);
            ob[j] = MFMA16(pb1, vc1[j], ob[j]);
        }
    };

    // --- ping-pong main loop: prefetch kt+1 while computing kt ---
    bf16x8 ka0[4], ka1[4], va0[4], va1[4];      // set A
    bf16x8 kb0[4], kb1[4], vb0[4], vb1[4];      // set B
    tload(0, ka0, ka1, va0, va1);
    int kt = 0;
    for (;;) {
        if (kt < qtw) tload(kt + 1, kb0, kb1, vb0, vb1);
        tcompute(kt, ka0, ka1, va0, va1);
        if (kt >= qtw) break;
        kt++;
        if (kt < qtw) tload(kt + 1, ka0, ka1, va0, va1);
        tcompute(kt, kb0, kb1, vb0, vb1);
        if (kt >= qtw) break;
        kt++;
    }

    // --- reduce l across the 16 col-lanes of each quad group ---
#pragma unroll
    for (int off = 1; off < 16; off <<= 1)
#pragma unroll
        for (int r = 0; r < 4; r++) {
            la[r] += __shfl_xor(la[r], off, 64);
            lb[r] += __shfl_xor(lb[r], off, 64);
        }

#pragma unroll
    for (int j = 0; j < 4; j++) {
        const int d = j * 16 + col;
#pragma unroll
        for (int r = 0; r < 4; r++) {
            const int ta = qBase + wave * 32 + quad * 4 + r;
            aout[((size_t)(b * Tc + ta)) * Cc + h * 64 + d] =
                __float2bfloat16(oa[j][r] / la[r]);
            const int tb = ta + 16;
            aout[((size_t)(b * Tc + tb)) * Cc + h * 64 + d] =
                __float2bfloat16(ob[j][r] / lb[r]);
        }
    }
}

extern "C" void kernel_launch(void* const* d_in, const int* in_sizes, int n_in,
                              void* d_out, int out_size, void* d_ws, size_t ws_size,
                              hipStream_t stream) {
    const float* x = nullptr;
    const float* w_qkv = nullptr;
    const float* w_proj = nullptr;
    for (int i = 0; i < n_in; i++) {
        if (in_sizes[i] == 4194304) x = (const float*)d_in[i];
        else if (in_sizes[i] == 3145728) w_qkv = (const float*)d_in[i];
        else if (in_sizes[i] == 1048576) w_proj = (const float*)d_in[i];
    }
    float* out = (float*)d_out;

    __hip_bfloat16* qkv = (__hip_bfloat16*)d_ws;        // q[4M] k[4M] v[4M]
    __hip_bfloat16* vbuf = qkv + 2 * QKV_STRIDE;        // v slot; becomes ao
    __hip_bfloat16* vt = qkv + 3 * QKV_STRIDE;          // 4M
    __hip_bfloat16* ao = vbuf;                          // attn out over dead v

    gemm_qkv<<<dim3(4096 / 128, 3072 / 128), 256, 0, stream>>>(x, w_qkv, qkv);
    transpose_v<<<dim3(Tc / 64, Hc, Bc), 256, 0, stream>>>(vbuf, vt);
    attn_kernel<<<dim3(Tc / 128, Hc, Bc), 256, 0, stream>>>(qkv, vt, ao);
    gemm_proj<<<dim3(4096 / 128, 1024 / 64), 256, 0, stream>>>(ao, w_proj, out);
}

// Round 3
// 257.565 us; speedup vs baseline: 1.0401x; 1.0401x over previous
//
#include <hip/hip_runtime.h>
#include <hip/hip_bf16.h>

// ROUND 12b: split-K flash attention (retry — hipMemsetAsync removed).
// R12 bench failed container-side; the graph-capture-risky call was
// hipMemsetAsync in kernel_launch. Replaced with a zero_acc kernel.
// Design unchanged: m=0 softmax => partial (O,l) over disjoint key slices
// sum linearly. One 64-thread wave per (b,h,32q-chunk,8-tile key slice)
// -> 5120 units, straggler 8 tiles, ~4 waves/SIMD. Partials atomicAdd into
// f32 accum; attn_norm divides + packs bf16. ws_size-checked fallback to R10.
// ws: qkv[24MB] vt[8MB] (ao overlays v) | accO[16MB] accL[0.25MB] = 50.6MB.

typedef __attribute__((ext_vector_type(8))) short bf16x8;
typedef __attribute__((ext_vector_type(4))) short bf16x4;
typedef __attribute__((ext_vector_type(4))) float floatx4;

#define MFMA16(a, b, c) __builtin_amdgcn_mfma_f32_16x16x32_bf16((a), (b), (c), 0, 0, 0)

#if __has_builtin(__builtin_amdgcn_exp2f)
#define EXP2F(x) __builtin_amdgcn_exp2f(x)
#else
#define EXP2F(x) exp2f(x)
#endif

static constexpr int Bc = 2, Tc = 2048, Cc = 1024, Hc = 16, Dc = 64;
static constexpr size_t QKV_STRIDE = (size_t)Bc * Hc * Tc * Dc; // 4194304
static constexpr float KSL2E = 0.125f * 1.44269504088896f; // scale * log2(e)

__device__ __forceinline__ bf16x8 load8(const __hip_bfloat16* p) {
    return *(const bf16x8*)p;
}

__device__ __forceinline__ bf16x8 load8_lds(const __hip_bfloat16* p) {
    const bf16x4 lo = *(const bf16x4*)p;
    const bf16x4 hi = *(const bf16x4*)(p + 4);
    bf16x8 r;
    r[0] = lo[0]; r[1] = lo[1]; r[2] = lo[2]; r[3] = lo[3];
    r[4] = hi[0]; r[5] = hi[1]; r[6] = hi[2]; r[7] = hi[3];
    return r;
}

__device__ __forceinline__ short f2b(float x) {
    union { __hip_bfloat16 h; short s; } u;
    u.h = __float2bfloat16(x);
    return u.s;
}

__device__ __forceinline__ bf16x8 pack8(floatx4 a, floatx4 b) {
    bf16x8 r;
    r[0] = f2b(a[0]); r[1] = f2b(a[1]); r[2] = f2b(a[2]); r[3] = f2b(a[3]);
    r[4] = f2b(b[0]); r[5] = f2b(b[1]); r[6] = f2b(b[2]); r[7] = f2b(b[3]);
    return r;
}

__device__ __forceinline__ void gl2lds16(const void* g, void* l) {
    __builtin_amdgcn_global_load_lds(
        (const __attribute__((address_space(1))) void*)g,
        (__attribute__((address_space(3))) void*)l, 16, 0, 0);
}

// ================= GEMM1 (unchanged): qkv = x @ w_qkv^T =====================
__global__ __launch_bounds__(256) void gemm_qkv(
    const float* __restrict__ A,
    const float* __restrict__ W,
    __hip_bfloat16* __restrict__ qkv) {
    __shared__ float As[128 * 32];
    __shared__ float Bs[128 * 32];
    const int K = Cc;
    const int lane = threadIdx.x & 63;
    const int wave = threadIdx.x >> 6;
    const int waveM = wave >> 1, waveN = wave & 1;
    const int mBase = blockIdx.x * 128;
    const int nBase = blockIdx.y * 128;
    const int idx16 = lane & 15;
    const int quad = lane >> 4;

    const int ldRow = lane >> 3;
    const int ldPos = lane & 7;

    floatx4 acc[4][4] = {};

    for (int k0 = 0; k0 < K; k0 += 32) {
        __syncthreads();
#pragma unroll
        for (int s = 0; s < 4; s++) {
            const int r0 = wave * 32 + s * 8;
            const int row = r0 + ldRow;
            const int cg = ldPos ^ (row & 7);
            gl2lds16(A + (size_t)(mBase + row) * K + k0 + cg * 4, &As[r0 * 32]);
            gl2lds16(W + (size_t)(nBase + row) * K + k0 + cg * 4, &Bs[r0 * 32]);
        }
        __syncthreads();

        bf16x8 af[4], bfr[4];
#pragma unroll
        for (int i = 0; i < 4; i++) {
            const int rr = waveM * 64 + i * 16 + idx16;
            const floatx4 a0 = *(const floatx4*)&As[rr * 32 + (((quad * 2) ^ (rr & 7)) * 4)];
            const floatx4 a1 = *(const floatx4*)&As[rr * 32 + (((quad * 2 + 1) ^ (rr & 7)) * 4)];
            af[i] = pack8(a0, a1);
        }
#pragma unroll
        for (int j = 0; j < 4; j++) {
            const int rr = waveN * 64 + j * 16 + idx16;
            const floatx4 b0 = *(const floatx4*)&Bs[rr * 32 + (((quad * 2) ^ (rr & 7)) * 4)];
            const floatx4 b1 = *(const floatx4*)&Bs[rr * 32 + (((quad * 2 + 1) ^ (rr & 7)) * 4)];
            bfr[j] = pack8(b0, b1);
        }
#pragma unroll
        for (int i = 0; i < 4; i++)
#pragma unroll
            for (int j = 0; j < 4; j++)
                acc[i][j] = MFMA16(af[i], bfr[j], acc[i][j]);
    }

#pragma unroll
    for (int i = 0; i < 4; i++) {
#pragma unroll
        for (int j = 0; j < 4; j++) {
            const int n = nBase + waveN * 64 + j * 16 + idx16;
            const int part = n >> 10;
            const int rem = n & 1023;
            const int h = rem >> 6, d = rem & 63;
#pragma unroll
            for (int r = 0; r < 4; r++) {
                const int m = mBase + waveM * 64 + i * 16 + quad * 4 + r;
                const int bb = m >> 11, t = m & 2047;
                const size_t o = (size_t)part * QKV_STRIDE +
                                 (((size_t)(bb * Hc + h)) * Tc + t) * Dc + d;
                qkv[o] = __float2bfloat16(acc[i][j][r]);
            }
        }
    }
}

// ================= GEMM2 (unchanged): out(f32) = ao @ w_proj^T ==============
__global__ __launch_bounds__(256) void gemm_proj(
    const __hip_bfloat16* __restrict__ A,
    const float* __restrict__ W,
    float* __restrict__ out) {
    __shared__ __hip_bfloat16 As16[128 * 32];
    __shared__ float Ws[64 * 32];
    const int K = Cc;
    const int lane = threadIdx.x & 63;
    const int wave = threadIdx.x >> 6;
    const int waveM = wave >> 1, waveN = wave & 1;
    const int mBase = blockIdx.x * 128;
    const int nBase = blockIdx.y * 64;
    const int idx16 = lane & 15;
    const int quad = lane >> 4;

    const int aRow = lane >> 2, aPos = lane & 3;
    const int wRow = lane >> 3, wPos = lane & 7;

    floatx4 acc[4][2] = {};

    for (int k0 = 0; k0 < K; k0 += 32) {
        __syncthreads();
#pragma unroll
        for (int s = 0; s < 2; s++) {
            {
                const int r0 = wave * 32 + s * 16;
                const int row = r0 + aRow;
                const int cg = aPos ^ (row & 3);
                gl2lds16(A + (size_t)(mBase + row) * K + k0 + cg * 8, &As16[r0 * 32]);
            }
            {
                const int r0 = wave * 16 + s * 8;
                const int row = r0 + wRow;
                const int cg = wPos ^ (row & 7);
                gl2lds16(W + (size_t)(nBase + row) * K + k0 + cg * 4, &Ws[r0 * 32]);
            }
        }
        __syncthreads();

        bf16x8 af[4], bfr[2];
#pragma unroll
        for (int i = 0; i < 4; i++) {
            const int rr = waveM * 64 + i * 16 + idx16;
            af[i] = *(const bf16x8*)&As16[rr * 32 + ((quad ^ (rr & 3)) * 8)];
        }
#pragma unroll
        for (int j = 0; j < 2; j++) {
            const int rr = waveN * 32 + j * 16 + idx16;
            const floatx4 b0 = *(const floatx4*)&Ws[rr * 32 + (((quad * 2) ^ (rr & 7)) * 4)];
            const floatx4 b1 = *(const floatx4*)&Ws[rr * 32 + (((quad * 2 + 1) ^ (rr & 7)) * 4)];
            bfr[j] = pack8(b0, b1);
        }
#pragma unroll
        for (int i = 0; i < 4; i++)
#pragma unroll
            for (int j = 0; j < 2; j++)
                acc[i][j] = MFMA16(af[i], bfr[j], acc[i][j]);
    }

#pragma unroll
    for (int i = 0; i < 4; i++) {
#pragma unroll
        for (int j = 0; j < 2; j++) {
            const int n = nBase + waveN * 32 + j * 16 + idx16;
#pragma unroll
            for (int r = 0; r < 4; r++) {
                const int m = mBase + waveM * 64 + i * 16 + quad * 4 + r;
                out[(size_t)m * Cc + n] = acc[i][j][r];
            }
        }
    }
}

// ================= V transpose (unchanged): [b,h,t,d] -> [b,h,d,t] ==========
__global__ __launch_bounds__(256) void transpose_v(
    const __hip_bfloat16* __restrict__ v,
    __hip_bfloat16* __restrict__ vt) {
    __shared__ unsigned short tile[64][65];
    const int t0 = blockIdx.x * 64;
    const int h = blockIdx.y, b = blockIdx.z;
    const size_t base = ((size_t)(b * Hc + h)) * Tc * Dc;
    const unsigned short* vp = (const unsigned short*)v + base;
    unsigned short* vtp = (unsigned short*)vt + base;

    for (int e = threadIdx.x; e < 4096; e += 256) {
        const int tl = e >> 6, d = e & 63;
        tile[tl][d] = vp[(size_t)(t0 + tl) * Dc + d];
    }
    __syncthreads();
    for (int e = threadIdx.x; e < 4096; e += 256) {
        const int d = e >> 6, tl = e & 63;
        vtp[(size_t)d * Tc + t0 + tl] = tile[tl][d];
    }
}

// ================= zero accumulators (replaces hipMemsetAsync) ==============
__global__ __launch_bounds__(256) void zero_acc(float* __restrict__ p, int n4) {
    const int i = blockIdx.x * 256 + threadIdx.x;
    if (i < n4) {
        floatx4 z = {0.f, 0.f, 0.f, 0.f};
        *(floatx4*)&p[(size_t)i * 4] = z;
    }
}

// ================= Flash attention v5: split-K, 1 wave / unit ===============
// Unit = (b, h, 32-q chunk w, key-slice s of 8 x 64-key tiles). m=0 softmax:
// partial (O,l) over disjoint key ranges sum linearly -> atomicAdd f32 accum.
// 64-thread blocks, ~112 VGPR, 4.6KB LDS -> up to 4 waves/SIMD resident.
__global__ __launch_bounds__(64) void attn_split(
    const __hip_bfloat16* __restrict__ qkv,
    const __hip_bfloat16* __restrict__ vt,
    float* __restrict__ accO,
    float* __restrict__ accL) {
    __shared__ __hip_bfloat16 lds_p[2][16][72];

    const int lane = threadIdx.x;
    const int col = lane & 15;
    const int quad = lane >> 4;
    const int w = 63 - (int)blockIdx.x;          // heavy chunks first
    const int s = blockIdx.y;                    // key slice
    const int bh = blockIdx.z;
    const int h = bh & 15, b = bh >> 4;
    const int qBase = w * 32;
    const int nt = ((qBase + 31) >> 6) + 1;      // total K-tiles this chunk
    const int kt0 = s * 8;
    if (kt0 >= nt) return;
    const int ktEnd = min(nt, kt0 + 8);

    const size_t headOff = ((size_t)(b * Hc + h)) * Tc * Dc;
    const __hip_bfloat16* qp = qkv + headOff;
    const __hip_bfloat16* kp = qkv + QKV_STRIDE + headOff;
    const __hip_bfloat16* vtp = vt + headOff;    // [d][t] within head

    const int qrowA = qBase + col;               // frag A rows
    const int qrowB = qrowA + 16;                // frag B rows
    bf16x8 qfa[2], qfb[2];
    qfa[0] = load8(qp + (size_t)qrowA * Dc + quad * 8);
    qfa[1] = load8(qp + (size_t)qrowA * Dc + 32 + quad * 8);
    qfb[0] = load8(qp + (size_t)qrowB * Dc + quad * 8);
    qfb[1] = load8(qp + (size_t)qrowB * Dc + 32 + quad * 8);

    floatx4 oa[4] = {}, ob[4] = {};
    float la[4] = {0.f, 0.f, 0.f, 0.f}, lb[4] = {0.f, 0.f, 0.f, 0.f};
    const int q0a = qBase + quad * 4;
    const int q0b = q0a + 16;

    for (int kt = kt0; kt < ktEnd; kt++) {
        const int keyBase = kt * 64;

        // --- issue ALL tile loads up front (K first, then Vt) ---
        bf16x8 kc0[4], kc1[4], vc0[4], vc1[4];
#pragma unroll
        for (int j = 0; j < 4; j++) {
            const int key = keyBase + j * 16 + col;
            kc0[j] = load8(kp + (size_t)key * Dc + quad * 8);
            kc1[j] = load8(kp + (size_t)key * Dc + 32 + quad * 8);
        }
#pragma unroll
        for (int j = 0; j < 4; j++) {
            const int d = j * 16 + col;
            vc0[j] = load8(vtp + (size_t)d * Tc + keyBase + quad * 8);
            vc1[j] = load8(vtp + (size_t)d * Tc + keyBase + 32 + quad * 8);
        }

        // --- S = Q K^T for both q-frags ---
        floatx4 sa[4], sb[4];
#pragma unroll
        for (int j = 0; j < 4; j++) {
            floatx4 a0 = {0.f, 0.f, 0.f, 0.f};
            a0 = MFMA16(qfa[0], kc0[j], a0);
            sa[j] = MFMA16(qfa[1], kc1[j], a0);
            floatx4 b0 = {0.f, 0.f, 0.f, 0.f};
            b0 = MFMA16(qfb[0], kc0[j], b0);
            sb[j] = MFMA16(qfb[1], kc1[j], b0);
        }

        // --- P = exp2(s*KSL2E), branchless causal mask, per-lane l ---
#pragma unroll
        for (int j = 0; j < 4; j++) {
            const int key = keyBase + j * 16 + col;
#pragma unroll
            for (int r = 0; r < 4; r++) {
                float pa = EXP2F(sa[j][r] * KSL2E);
                pa = (key > q0a + r) ? 0.f : pa;
                la[r] += pa;
                lds_p[0][quad * 4 + r][j * 16 + col] = __float2bfloat16(pa);
                float pb = EXP2F(sb[j][r] * KSL2E);
                pb = (key > q0b + r) ? 0.f : pb;
                lb[r] += pb;
                lds_p[1][quad * 4 + r][j * 16 + col] = __float2bfloat16(pb);
            }
        }

        // --- O += P V (P A-frags from wave-private LDS; Vt from regs) ---
        const bf16x8 pa0 = load8_lds(&lds_p[0][col][quad * 8]);
        const bf16x8 pa1 = load8_lds(&lds_p[0][col][32 + quad * 8]);
        const bf16x8 pb0 = load8_lds(&lds_p[1][col][quad * 8]);
        const bf16x8 pb1 = load8_lds(&lds_p[1][col][32 + quad * 8]);
#pragma unroll
        for (int j = 0; j < 4; j++) {
            oa[j] = MFMA16(pa0, vc0[j], oa[j]);
            oa[j] = MFMA16(pa1, vc1[j], oa[j]);
            ob[j] = MFMA16(pb0, vc0[j], ob[j]);
            ob[j] = MFMA16(pb1, vc1[j], ob[j]);
        }
    }

    // --- reduce l across the 16 col-lanes of each quad group ---
#pragma unroll
    for (int off = 1; off < 16; off <<= 1)
#pragma unroll
        for (int r = 0; r < 4; r++) {
            la[r] += __shfl_xor(la[r], off, 64);
            lb[r] += __shfl_xor(lb[r], off, 64);
        }

    // --- accumulate partials: O (all lanes) and l (col==0 lanes) ---
#pragma unroll
    for (int j = 0; j < 4; j++) {
        const int d = j * 16 + col;
#pragma unroll
        for (int r = 0; r < 4; r++) {
            const int ta = q0a + r;
            atomicAdd(&accO[((size_t)(b * Tc + ta)) * Cc + h * 64 + d], oa[j][r]);
            const int tb = q0b + r;
            atomicAdd(&accO[((size_t)(b * Tc + tb)) * Cc + h * 64 + d], ob[j][r]);
        }
    }
    if (col == 0) {
#pragma unroll
        for (int r = 0; r < 4; r++) {
            atomicAdd(&accL[((size_t)(b * Tc + q0a + r)) * Hc + h], la[r]);
            atomicAdd(&accL[((size_t)(b * Tc + q0b + r)) * Hc + h], lb[r]);
        }
    }
}

// ================= normalize: ao(bf16) = accO / accL ========================
__global__ __launch_bounds__(256) void attn_norm(
    const float* __restrict__ accO,
    const float* __restrict__ accL,
    __hip_bfloat16* __restrict__ ao) {
    const int idx = blockIdx.x * 256 + threadIdx.x;  // 1M threads, 4 elems each
    const int m = idx >> 8;
    const int c4 = (idx & 255) << 2;
    const floatx4 o = *(const floatx4*)&accO[(size_t)m * Cc + c4];
    const float inv = 1.0f / accL[(size_t)m * Hc + (c4 >> 6)];
    bf16x4 r;
    r[0] = f2b(o[0] * inv); r[1] = f2b(o[1] * inv);
    r[2] = f2b(o[2] * inv); r[3] = f2b(o[3] * inv);
    *(bf16x4*)&ao[(size_t)m * Cc + c4] = r;
}

// ================= Fallback (R10): 4-wave attn, direct output ===============
__global__ __launch_bounds__(256) void attn_kernel(
    const __hip_bfloat16* __restrict__ qkv,
    const __hip_bfloat16* __restrict__ vt,
    __hip_bfloat16* __restrict__ aout) {
    __shared__ __hip_bfloat16 lds_p[4][2][16][72];

    const int lane = threadIdx.x & 63;
    const int wave = threadIdx.x >> 6;
    const int col = lane & 15;
    const int quad = lane >> 4;
    const int qt = (gridDim.x - 1) - blockIdx.x;
    const int h = blockIdx.y;
    const int b = blockIdx.z;
    const int qBase = qt * 128;

    const size_t headOff = ((size_t)(b * Hc + h)) * Tc * Dc;
    const __hip_bfloat16* qp = qkv + headOff;
    const __hip_bfloat16* kp = qkv + QKV_STRIDE + headOff;
    const __hip_bfloat16* vtp = vt + headOff;

    const int qrowA = qBase + wave * 32 + col;
    const int qrowB = qrowA + 16;
    bf16x8 qfa[2], qfb[2];
    qfa[0] = load8(qp + (size_t)qrowA * Dc + quad * 8);
    qfa[1] = load8(qp + (size_t)qrowA * Dc + 32 + quad * 8);
    qfb[0] = load8(qp + (size_t)qrowB * Dc + quad * 8);
    qfb[1] = load8(qp + (size_t)qrowB * Dc + 32 + quad * 8);

    floatx4 oa[4] = {}, ob[4] = {};
    float la[4] = {0.f, 0.f, 0.f, 0.f}, lb[4] = {0.f, 0.f, 0.f, 0.f};
    const int q0a = qBase + wave * 32 + quad * 4;
    const int q0b = q0a + 16;
    const int qtw = (qBase + wave * 32 + 31) >> 6;

    for (int kt = 0; kt <= qtw; kt++) {
        const int keyBase = kt * 64;
        bf16x8 kc0[4], kc1[4], vc0[4], vc1[4];
#pragma unroll
        for (int j = 0; j < 4; j++) {
            const int key = keyBase + j * 16 + col;
            kc0[j] = load8(kp + (size_t)key * Dc + quad * 8);
            kc1[j] = load8(kp + (size_t)key * Dc + 32 + quad * 8);
        }
#pragma unroll
        for (int j = 0; j < 4; j++) {
            const int d = j * 16 + col;
            vc0[j] = load8(vtp + (size_t)d * Tc + keyBase + quad * 8);
            vc1[j] = load8(vtp + (size_t)d * Tc + keyBase + 32 + quad * 8);
        }

        floatx4 sa[4], sb[4];
#pragma unroll
        for (int j = 0; j < 4; j++) {
            floatx4 a0 = {0.f, 0.f, 0.f, 0.f};
            a0 = MFMA16(qfa[0], kc0[j], a0);
            sa[j] = MFMA16(qfa[1], kc1[j], a0);
            floatx4 b0 = {0.f, 0.f, 0.f, 0.f};
            b0 = MFMA16(qfb[0], kc0[j], b0);
            sb[j] = MFMA16(qfb[1], kc1[j], b0);
        }

#pragma unroll
        for (int j = 0; j < 4; j++) {
            const int key = keyBase + j * 16 + col;
#pragma unroll
            for (int r = 0; r < 4; r++) {
                float pa = EXP2F(sa[j][r] * KSL2E);
                pa = (key > q0a + r) ? 0.f : pa;
                la[r] += pa;
                lds_p[wave][0][quad * 4 + r][j * 16 + col] = __float2bfloat16(pa);
                float pb = EXP2F(sb[j][r] * KSL2E);
                pb = (key > q0b + r) ? 0.f : pb;
                lb[r] += pb;
                lds_p[wave][1][quad * 4 + r][j * 16 + col] = __float2bfloat16(pb);
            }
        }

        const bf16x8 pa0 = load8_lds(&lds_p[wave][0][col][quad * 8]);
        const bf16x8 pa1 = load8_lds(&lds_p[wave][0][col][32 + quad * 8]);
        const bf16x8 pb0 = load8_lds(&lds_p[wave][1][col][quad * 8]);
        const bf16x8 pb1 = load8_lds(&lds_p[wave][1][col][32 + quad * 8]);
#pragma unroll
        for (int j = 0; j < 4; j++) {
            oa[j] = MFMA16(pa0, vc0[j], oa[j]);
            oa[j] = MFMA16(pa1, vc1[j], oa[j]);
            ob[j] = MFMA16(pb0, vc0[j], ob[j]);
            ob[j] = MFMA16(pb1, vc1[j], ob[j]);
        }
    }

#pragma unroll
    for (int off = 1; off < 16; off <<= 1)
#pragma unroll
        for (int r = 0; r < 4; r++) {
            la[r] += __shfl_xor(la[r], off, 64);
            lb[r] += __shfl_xor(lb[r], off, 64);
        }

#pragma unroll
    for (int j = 0; j < 4; j++) {
        const int d = j * 16 + col;
#pragma unroll
        for (int r = 0; r < 4; r++) {
            const int ta = qBase + wave * 32 + quad * 4 + r;
            aout[((size_t)(b * Tc + ta)) * Cc + h * 64 + d] =
                __float2bfloat16(oa[j][r] / la[r]);
            const int tb = ta + 16;
            aout[((size_t)(b * Tc + tb)) * Cc + h * 64 + d] =
                __float2bfloat16(ob[j][r] / lb[r]);
        }
    }
}

extern "C" void kernel_launch(void* const* d_in, const int* in_sizes, int n_in,
                              void* d_out, int out_size, void* d_ws, size_t ws_size,
                              hipStream_t stream) {
    const float* x = nullptr;
    const float* w_qkv = nullptr;
    const float* w_proj = nullptr;
    for (int i = 0; i < n_in; i++) {
        if (in_sizes[i] == 4194304) x = (const float*)d_in[i];
        else if (in_sizes[i] == 3145728) w_qkv = (const float*)d_in[i];
        else if (in_sizes[i] == 1048576) w_proj = (const float*)d_in[i];
    }
    float* out = (float*)d_out;

    __hip_bfloat16* qkv = (__hip_bfloat16*)d_ws;        // q[4M] k[4M] v[4M]
    __hip_bfloat16* vbuf = qkv + 2 * QKV_STRIDE;        // v slot; becomes ao
    __hip_bfloat16* vt = qkv + 3 * QKV_STRIDE;          // 4M elems
    __hip_bfloat16* ao = vbuf;                          // attn out over dead v

    // split-K accumulators: after qkv+vt (8*QKV_STRIDE bytes = 32MB offset)
    const size_t ACC_OFF = 8 * QKV_STRIDE;              // bytes
    const size_t N_O = (size_t)Bc * Tc * Cc;            // 4194304 f32
    const size_t N_L = (size_t)Bc * Tc * Hc;            // 65536 f32
    const size_t NEED = ACC_OFF + (N_O + N_L) * sizeof(float);

    gemm_qkv<<<dim3(4096 / 128, 3072 / 128), 256, 0, stream>>>(x, w_qkv, qkv);
    transpose_v<<<dim3(Tc / 64, Hc, Bc), 256, 0, stream>>>(vbuf, vt);

    if (ws_size >= NEED) {
        float* accO = (float*)((char*)d_ws + ACC_OFF);
        float* accL = accO + N_O;
        const int n4 = (int)((N_O + N_L) / 4);          // 1064960 float4 groups
        zero_acc<<<dim3((n4 + 255) / 256), 256, 0, stream>>>(accO, n4);
        attn_split<<<dim3(64, 4, 32), 64, 0, stream>>>(qkv, vt, accO, accL);
        attn_norm<<<dim3((Bc * Tc * Cc / 4) / 256), 256, 0, stream>>>(accO, accL, ao);
    } else {
        attn_kernel<<<dim3(Tc / 128, Hc, Bc), 256, 0, stream>>>(qkv, vt, ao);
    }

    gemm_proj<<<dim3(4096 / 128, 1024 / 64), 256, 0, stream>>>(ao, w_proj, out);
}

// Round 4
// 253.075 us; speedup vs baseline: 1.0585x; 1.0177x over previous
//
#include <hip/hip_runtime.h>
#include <hip/hip_bf16.h>

// ROUND 13: split-K attention, 4 units per 256-thread block.
// R12b post-mortem: 8192 one-wave blocks -> only ~4 waves/CU resident
// (workgroup-slot/dispatch limited), so split-K parallelism never became
// residency. Fix: flatten the 160 (chunk,slice) units per (b,h) into a dense
// list, 1 unit per wave, 4 waves per block -> 1280 full blocks, no early
// exits. VGPR-bound residency: 4 blocks/CU x 4 waves = 16 waves/CU (4/SIMD).
// Tile-loop code identical to R12b. GEMMs/transpose/norm unchanged.
// ws: qkv[24MB] vt[8MB] (ao overlays v) | accO[16MB] accL[0.25MB] = 50.6MB.

typedef __attribute__((ext_vector_type(8))) short bf16x8;
typedef __attribute__((ext_vector_type(4))) short bf16x4;
typedef __attribute__((ext_vector_type(4))) float floatx4;

#define MFMA16(a, b, c) __builtin_amdgcn_mfma_f32_16x16x32_bf16((a), (b), (c), 0, 0, 0)

#if __has_builtin(__builtin_amdgcn_exp2f)
#define EXP2F(x) __builtin_amdgcn_exp2f(x)
#else
#define EXP2F(x) exp2f(x)
#endif

static constexpr int Bc = 2, Tc = 2048, Cc = 1024, Hc = 16, Dc = 64;
static constexpr size_t QKV_STRIDE = (size_t)Bc * Hc * Tc * Dc; // 4194304
static constexpr float KSL2E = 0.125f * 1.44269504088896f; // scale * log2(e)

__device__ __forceinline__ bf16x8 load8(const __hip_bfloat16* p) {
    return *(const bf16x8*)p;
}

__device__ __forceinline__ bf16x8 load8_lds(const __hip_bfloat16* p) {
    const bf16x4 lo = *(const bf16x4*)p;
    const bf16x4 hi = *(const bf16x4*)(p + 4);
    bf16x8 r;
    r[0] = lo[0]; r[1] = lo[1]; r[2] = lo[2]; r[3] = lo[3];
    r[4] = hi[0]; r[5] = hi[1]; r[6] = hi[2]; r[7] = hi[3];
    return r;
}

__device__ __forceinline__ short f2b(float x) {
    union { __hip_bfloat16 h; short s; } u;
    u.h = __float2bfloat16(x);
    return u.s;
}

__device__ __forceinline__ bf16x8 pack8(floatx4 a, floatx4 b) {
    bf16x8 r;
    r[0] = f2b(a[0]); r[1] = f2b(a[1]); r[2] = f2b(a[2]); r[3] = f2b(a[3]);
    r[4] = f2b(b[0]); r[5] = f2b(b[1]); r[6] = f2b(b[2]); r[7] = f2b(b[3]);
    return r;
}

__device__ __forceinline__ void gl2lds16(const void* g, void* l) {
    __builtin_amdgcn_global_load_lds(
        (const __attribute__((address_space(1))) void*)g,
        (__attribute__((address_space(3))) void*)l, 16, 0, 0);
}

// ================= GEMM1 (unchanged): qkv = x @ w_qkv^T =====================
__global__ __launch_bounds__(256) void gemm_qkv(
    const float* __restrict__ A,
    const float* __restrict__ W,
    __hip_bfloat16* __restrict__ qkv) {
    __shared__ float As[128 * 32];
    __shared__ float Bs[128 * 32];
    const int K = Cc;
    const int lane = threadIdx.x & 63;
    const int wave = threadIdx.x >> 6;
    const int waveM = wave >> 1, waveN = wave & 1;
    const int mBase = blockIdx.x * 128;
    const int nBase = blockIdx.y * 128;
    const int idx16 = lane & 15;
    const int quad = lane >> 4;

    const int ldRow = lane >> 3;
    const int ldPos = lane & 7;

    floatx4 acc[4][4] = {};

    for (int k0 = 0; k0 < K; k0 += 32) {
        __syncthreads();
#pragma unroll
        for (int s = 0; s < 4; s++) {
            const int r0 = wave * 32 + s * 8;
            const int row = r0 + ldRow;
            const int cg = ldPos ^ (row & 7);
            gl2lds16(A + (size_t)(mBase + row) * K + k0 + cg * 4, &As[r0 * 32]);
            gl2lds16(W + (size_t)(nBase + row) * K + k0 + cg * 4, &Bs[r0 * 32]);
        }
        __syncthreads();

        bf16x8 af[4], bfr[4];
#pragma unroll
        for (int i = 0; i < 4; i++) {
            const int rr = waveM * 64 + i * 16 + idx16;
            const floatx4 a0 = *(const floatx4*)&As[rr * 32 + (((quad * 2) ^ (rr & 7)) * 4)];
            const floatx4 a1 = *(const floatx4*)&As[rr * 32 + (((quad * 2 + 1) ^ (rr & 7)) * 4)];
            af[i] = pack8(a0, a1);
        }
#pragma unroll
        for (int j = 0; j < 4; j++) {
            const int rr = waveN * 64 + j * 16 + idx16;
            const floatx4 b0 = *(const floatx4*)&Bs[rr * 32 + (((quad * 2) ^ (rr & 7)) * 4)];
            const floatx4 b1 = *(const floatx4*)&Bs[rr * 32 + (((quad * 2 + 1) ^ (rr & 7)) * 4)];
            bfr[j] = pack8(b0, b1);
        }
#pragma unroll
        for (int i = 0; i < 4; i++)
#pragma unroll
            for (int j = 0; j < 4; j++)
                acc[i][j] = MFMA16(af[i], bfr[j], acc[i][j]);
    }

#pragma unroll
    for (int i = 0; i < 4; i++) {
#pragma unroll
        for (int j = 0; j < 4; j++) {
            const int n = nBase + waveN * 64 + j * 16 + idx16;
            const int part = n >> 10;
            const int rem = n & 1023;
            const int h = rem >> 6, d = rem & 63;
#pragma unroll
            for (int r = 0; r < 4; r++) {
                const int m = mBase + waveM * 64 + i * 16 + quad * 4 + r;
                const int bb = m >> 11, t = m & 2047;
                const size_t o = (size_t)part * QKV_STRIDE +
                                 (((size_t)(bb * Hc + h)) * Tc + t) * Dc + d;
                qkv[o] = __float2bfloat16(acc[i][j][r]);
            }
        }
    }
}

// ================= GEMM2 (unchanged): out(f32) = ao @ w_proj^T ==============
__global__ __launch_bounds__(256) void gemm_proj(
    const __hip_bfloat16* __restrict__ A,
    const float* __restrict__ W,
    float* __restrict__ out) {
    __shared__ __hip_bfloat16 As16[128 * 32];
    __shared__ float Ws[64 * 32];
    const int K = Cc;
    const int lane = threadIdx.x & 63;
    const int wave = threadIdx.x >> 6;
    const int waveM = wave >> 1, waveN = wave & 1;
    const int mBase = blockIdx.x * 128;
    const int nBase = blockIdx.y * 64;
    const int idx16 = lane & 15;
    const int quad = lane >> 4;

    const int aRow = lane >> 2, aPos = lane & 3;
    const int wRow = lane >> 3, wPos = lane & 7;

    floatx4 acc[4][2] = {};

    for (int k0 = 0; k0 < K; k0 += 32) {
        __syncthreads();
#pragma unroll
        for (int s = 0; s < 2; s++) {
            {
                const int r0 = wave * 32 + s * 16;
                const int row = r0 + aRow;
                const int cg = aPos ^ (row & 3);
                gl2lds16(A + (size_t)(mBase + row) * K + k0 + cg * 8, &As16[r0 * 32]);
            }
            {
                const int r0 = wave * 16 + s * 8;
                const int row = r0 + wRow;
                const int cg = wPos ^ (row & 7);
                gl2lds16(W + (size_t)(nBase + row) * K + k0 + cg * 4, &Ws[r0 * 32]);
            }
        }
        __syncthreads();

        bf16x8 af[4], bfr[2];
#pragma unroll
        for (int i = 0; i < 4; i++) {
            const int rr = waveM * 64 + i * 16 + idx16;
            af[i] = *(const bf16x8*)&As16[rr * 32 + ((quad ^ (rr & 3)) * 8)];
        }
#pragma unroll
        for (int j = 0; j < 2; j++) {
            const int rr = waveN * 32 + j * 16 + idx16;
            const floatx4 b0 = *(const floatx4*)&Ws[rr * 32 + (((quad * 2) ^ (rr & 7)) * 4)];
            const floatx4 b1 = *(const floatx4*)&Ws[rr * 32 + (((quad * 2 + 1) ^ (rr & 7)) * 4)];
            bfr[j] = pack8(b0, b1);
        }
#pragma unroll
        for (int i = 0; i < 4; i++)
#pragma unroll
            for (int j = 0; j < 2; j++)
                acc[i][j] = MFMA16(af[i], bfr[j], acc[i][j]);
    }

#pragma unroll
    for (int i = 0; i < 4; i++) {
#pragma unroll
        for (int j = 0; j < 2; j++) {
            const int n = nBase + waveN * 32 + j * 16 + idx16;
#pragma unroll
            for (int r = 0; r < 4; r++) {
                const int m = mBase + waveM * 64 + i * 16 + quad * 4 + r;
                out[(size_t)m * Cc + n] = acc[i][j][r];
            }
        }
    }
}

// ================= V transpose (unchanged): [b,h,t,d] -> [b,h,d,t] ==========
__global__ __launch_bounds__(256) void transpose_v(
    const __hip_bfloat16* __restrict__ v,
    __hip_bfloat16* __restrict__ vt) {
    __shared__ unsigned short tile[64][65];
    const int t0 = blockIdx.x * 64;
    const int h = blockIdx.y, b = blockIdx.z;
    const size_t base = ((size_t)(b * Hc + h)) * Tc * Dc;
    const unsigned short* vp = (const unsigned short*)v + base;
    unsigned short* vtp = (unsigned short*)vt + base;

    for (int e = threadIdx.x; e < 4096; e += 256) {
        const int tl = e >> 6, d = e & 63;
        tile[tl][d] = vp[(size_t)(t0 + tl) * Dc + d];
    }
    __syncthreads();
    for (int e = threadIdx.x; e < 4096; e += 256) {
        const int d = e >> 6, tl = e & 63;
        vtp[(size_t)d * Tc + t0 + tl] = tile[tl][d];
    }
}

// ================= zero accumulators ========================================
__global__ __launch_bounds__(256) void zero_acc(float* __restrict__ p, int n4) {
    const int i = blockIdx.x * 256 + threadIdx.x;
    if (i < n4) {
        floatx4 z = {0.f, 0.f, 0.f, 0.f};
        *(floatx4*)&p[(size_t)i * 4] = z;
    }
}

// ================= Flash attention v6: split-K, 4 units / block =============
// Unit = (32-q chunk w, key-slice s of 8 x 64-key tiles); 160 units per (b,h)
// flattened dense (no early exits): u<16 ->(u,0); u<48 ->(16+(u-16)/2,..);
// u<96 ->(32+(u-48)/3,..); else (48+(u-96)/4,..). One unit per wave, 4 waves
// per block, heavy units first. m=0 softmax partials atomicAdd into f32 acc.
__global__ __launch_bounds__(256) void attn_split(
    const __hip_bfloat16* __restrict__ qkv,
    const __hip_bfloat16* __restrict__ vt,
    float* __restrict__ accO,
    float* __restrict__ accL) {
    __shared__ __hip_bfloat16 lds_p[4][2][16][72];  // per-wave slab

    const int lane = threadIdx.x & 63;
    const int wave = threadIdx.x >> 6;
    const int col = lane & 15;
    const int quad = lane >> 4;

    const int g = blockIdx.x * 4 + wave;         // 0..159
    const int u = 159 - g;                       // heavy units first
    int w, s;
    if (u < 16)      { w = u;                 s = 0; }
    else if (u < 48) { const int q = u - 16;  w = 16 + (q >> 1); s = q & 1; }
    else if (u < 96) { const int q = u - 48;  w = 32 + q / 3;    s = q % 3; }
    else             { const int q = u - 96;  w = 48 + (q >> 2); s = q & 3; }

    const int bh = blockIdx.y;
    const int h = bh & 15, b = bh >> 4;
    const int qBase = w * 32;
    const int nt = ((qBase + 31) >> 6) + 1;      // total K-tiles this chunk
    const int kt0 = s * 8;
    const int ktEnd = min(nt, kt0 + 8);

    const size_t headOff = ((size_t)(b * Hc + h)) * Tc * Dc;
    const __hip_bfloat16* qp = qkv + headOff;
    const __hip_bfloat16* kp = qkv + QKV_STRIDE + headOff;
    const __hip_bfloat16* vtp = vt + headOff;    // [d][t] within head

    const int qrowA = qBase + col;               // frag A rows
    const int qrowB = qrowA + 16;                // frag B rows
    bf16x8 qfa[2], qfb[2];
    qfa[0] = load8(qp + (size_t)qrowA * Dc + quad * 8);
    qfa[1] = load8(qp + (size_t)qrowA * Dc + 32 + quad * 8);
    qfb[0] = load8(qp + (size_t)qrowB * Dc + quad * 8);
    qfb[1] = load8(qp + (size_t)qrowB * Dc + 32 + quad * 8);

    floatx4 oa[4] = {}, ob[4] = {};
    float la[4] = {0.f, 0.f, 0.f, 0.f}, lb[4] = {0.f, 0.f, 0.f, 0.f};
    const int q0a = qBase + quad * 4;
    const int q0b = q0a + 16;

    for (int kt = kt0; kt < ktEnd; kt++) {
        const int keyBase = kt * 64;

        // --- issue ALL tile loads up front (K first, then Vt) ---
        bf16x8 kc0[4], kc1[4], vc0[4], vc1[4];
#pragma unroll
        for (int j = 0; j < 4; j++) {
            const int key = keyBase + j * 16 + col;
            kc0[j] = load8(kp + (size_t)key * Dc + quad * 8);
            kc1[j] = load8(kp + (size_t)key * Dc + 32 + quad * 8);
        }
#pragma unroll
        for (int j = 0; j < 4; j++) {
            const int d = j * 16 + col;
            vc0[j] = load8(vtp + (size_t)d * Tc + keyBase + quad * 8);
            vc1[j] = load8(vtp + (size_t)d * Tc + keyBase + 32 + quad * 8);
        }

        // --- S = Q K^T for both q-frags ---
        floatx4 sa[4], sb[4];
#pragma unroll
        for (int j = 0; j < 4; j++) {
            floatx4 a0 = {0.f, 0.f, 0.f, 0.f};
            a0 = MFMA16(qfa[0], kc0[j], a0);
            sa[j] = MFMA16(qfa[1], kc1[j], a0);
            floatx4 b0 = {0.f, 0.f, 0.f, 0.f};
            b0 = MFMA16(qfb[0], kc0[j], b0);
            sb[j] = MFMA16(qfb[1], kc1[j], b0);
        }

        // --- P = exp2(s*KSL2E), branchless causal mask, per-lane l ---
#pragma unroll
        for (int j = 0; j < 4; j++) {
            const int key = keyBase + j * 16 + col;
#pragma unroll
            for (int r = 0; r < 4; r++) {
                float pa = EXP2F(sa[j][r] * KSL2E);
                pa = (key > q0a + r) ? 0.f : pa;
                la[r] += pa;
                lds_p[wave][0][quad * 4 + r][j * 16 + col] = __float2bfloat16(pa);
                float pb = EXP2F(sb[j][r] * KSL2E);
                pb = (key > q0b + r) ? 0.f : pb;
                lb[r] += pb;
                lds_p[wave][1][quad * 4 + r][j * 16 + col] = __float2bfloat16(pb);
            }
        }

        // --- O += P V (P A-frags from wave-private LDS; Vt from regs) ---
        const bf16x8 pa0 = load8_lds(&lds_p[wave][0][col][quad * 8]);
        const bf16x8 pa1 = load8_lds(&lds_p[wave][0][col][32 + quad * 8]);
        const bf16x8 pb0 = load8_lds(&lds_p[wave][1][col][quad * 8]);
        const bf16x8 pb1 = load8_lds(&lds_p[wave][1][col][32 + quad * 8]);
#pragma unroll
        for (int j = 0; j < 4; j++) {
            oa[j] = MFMA16(pa0, vc0[j], oa[j]);
            oa[j] = MFMA16(pa1, vc1[j], oa[j]);
            ob[j] = MFMA16(pb0, vc0[j], ob[j]);
            ob[j] = MFMA16(pb1, vc1[j], ob[j]);
        }
    }

    // --- reduce l across the 16 col-lanes of each quad group ---
#pragma unroll
    for (int off = 1; off < 16; off <<= 1)
#pragma unroll
        for (int r = 0; r < 4; r++) {
            la[r] += __shfl_xor(la[r], off, 64);
            lb[r] += __shfl_xor(lb[r], off, 64);
        }

    // --- accumulate partials: O (all lanes) and l (col==0 lanes) ---
#pragma unroll
    for (int j = 0; j < 4; j++) {
        const int d = j * 16 + col;
#pragma unroll
        for (int r = 0; r < 4; r++) {
            const int ta = q0a + r;
            atomicAdd(&accO[((size_t)(b * Tc + ta)) * Cc + h * 64 + d], oa[j][r]);
            const int tb = q0b + r;
            atomicAdd(&accO[((size_t)(b * Tc + tb)) * Cc + h * 64 + d], ob[j][r]);
        }
    }
    if (col == 0) {
#pragma unroll
        for (int r = 0; r < 4; r++) {
            atomicAdd(&accL[((size_t)(b * Tc + q0a + r)) * Hc + h], la[r]);
            atomicAdd(&accL[((size_t)(b * Tc + q0b + r)) * Hc + h], lb[r]);
        }
    }
}

// ================= normalize: ao(bf16) = accO / accL ========================
__global__ __launch_bounds__(256) void attn_norm(
    const float* __restrict__ accO,
    const float* __restrict__ accL,
    __hip_bfloat16* __restrict__ ao) {
    const int idx = blockIdx.x * 256 + threadIdx.x;  // 1M threads, 4 elems each
    const int m = idx >> 8;
    const int c4 = (idx & 255) << 2;
    const floatx4 o = *(const floatx4*)&accO[(size_t)m * Cc + c4];
    const float inv = 1.0f / accL[(size_t)m * Hc + (c4 >> 6)];
    bf16x4 r;
    r[0] = f2b(o[0] * inv); r[1] = f2b(o[1] * inv);
    r[2] = f2b(o[2] * inv); r[3] = f2b(o[3] * inv);
    *(bf16x4*)&ao[(size_t)m * Cc + c4] = r;
}

// ================= Fallback (R10): 4-wave attn, direct output ===============
__global__ __launch_bounds__(256) void attn_kernel(
    const __hip_bfloat16* __restrict__ qkv,
    const __hip_bfloat16* __restrict__ vt,
    __hip_bfloat16* __restrict__ aout) {
    __shared__ __hip_bfloat16 lds_p[4][2][16][72];

    const int lane = threadIdx.x & 63;
    const int wave = threadIdx.x >> 6;
    const int col = lane & 15;
    const int quad = lane >> 4;
    const int qt = (gridDim.x - 1) - blockIdx.x;
    const int h = blockIdx.y;
    const int b = blockIdx.z;
    const int qBase = qt * 128;

    const size_t headOff = ((size_t)(b * Hc + h)) * Tc * Dc;
    const __hip_bfloat16* qp = qkv + headOff;
    const __hip_bfloat16* kp = qkv + QKV_STRIDE + headOff;
    const __hip_bfloat16* vtp = vt + headOff;

    const int qrowA = qBase + wave * 32 + col;
    const int qrowB = qrowA + 16;
    bf16x8 qfa[2], qfb[2];
    qfa[0] = load8(qp + (size_t)qrowA * Dc + quad * 8);
    qfa[1] = load8(qp + (size_t)qrowA * Dc + 32 + quad * 8);
    qfb[0] = load8(qp + (size_t)qrowB * Dc + quad * 8);
    qfb[1] = load8(qp + (size_t)qrowB * Dc + 32 + quad * 8);

    floatx4 oa[4] = {}, ob[4] = {};
    float la[4] = {0.f, 0.f, 0.f, 0.f}, lb[4] = {0.f, 0.f, 0.f, 0.f};
    const int q0a = qBase + wave * 32 + quad * 4;
    const int q0b = q0a + 16;
    const int qtw = (qBase + wave * 32 + 31) >> 6;

    for (int kt = 0; kt <= qtw; kt++) {
        const int keyBase = kt * 64;
        bf16x8 kc0[4], kc1[4], vc0[4], vc1[4];
#pragma unroll
        for (int j = 0; j < 4; j++) {
            const int key = keyBase + j * 16 + col;
            kc0[j] = load8(kp + (size_t)key * Dc + quad * 8);
            kc1[j] = load8(kp + (size_t)key * Dc + 32 + quad * 8);
        }
#pragma unroll
        for (int j = 0; j < 4; j++) {
            const int d = j * 16 + col;
            vc0[j] = load8(vtp + (size_t)d * Tc + keyBase + quad * 8);
            vc1[j] = load8(vtp + (size_t)d * Tc + keyBase + 32 + quad * 8);
        }

        floatx4 sa[4], sb[4];
#pragma unroll
        for (int j = 0; j < 4; j++) {
            floatx4 a0 = {0.f, 0.f, 0.f, 0.f};
            a0 = MFMA16(qfa[0], kc0[j], a0);
            sa[j] = MFMA16(qfa[1], kc1[j], a0);
            floatx4 b0 = {0.f, 0.f, 0.f, 0.f};
            b0 = MFMA16(qfb[0], kc0[j], b0);
            sb[j] = MFMA16(qfb[1], kc1[j], b0);
        }

#pragma unroll
        for (int j = 0; j < 4; j++) {
            const int key = keyBase + j * 16 + col;
#pragma unroll
            for (int r = 0; r < 4; r++) {
                float pa = EXP2F(sa[j][r] * KSL2E);
                pa = (key > q0a + r) ? 0.f : pa;
                la[r] += pa;
                lds_p[wave][0][quad * 4 + r][j * 16 + col] = __float2bfloat16(pa);
                float pb = EXP2F(sb[j][r] * KSL2E);
                pb = (key > q0b + r) ? 0.f : pb;
                lb[r] += pb;
                lds_p[wave][1][quad * 4 + r][j * 16 + col] = __float2bfloat16(pb);
            }
        }

        const bf16x8 pa0 = load8_lds(&lds_p[wave][0][col][quad * 8]);
        const bf16x8 pa1 = load8_lds(&lds_p[wave][0][col][32 + quad * 8]);
        const bf16x8 pb0 = load8_lds(&lds_p[wave][1][col][quad * 8]);
        const bf16x8 pb1 = load8_lds(&lds_p[wave][1][col][32 + quad * 8]);
#pragma unroll
        for (int j = 0; j < 4; j++) {
            oa[j] = MFMA16(pa0, vc0[j], oa[j]);
            oa[j] = MFMA16(pa1, vc1[j], oa[j]);
            ob[j] = MFMA16(pb0, vc0[j], ob[j]);
            ob[j] = MFMA16(pb1, vc1[j], ob[j]);
        }
    }

#pragma unroll
    for (int off = 1; off < 16; off <<= 1)
#pragma unroll
        for (int r = 0; r < 4; r++) {
            la[r] += __shfl_xor(la[r], off, 64);
            lb[r] += __shfl_xor(lb[r], off, 64);
        }

#pragma unroll
    for (int j = 0; j < 4; j++) {
        const int d = j * 16 + col;
#pragma unroll
        for (int r = 0; r < 4; r++) {
            const int ta = qBase + wave * 32 + quad * 4 + r;
            aout[((size_t)(b * Tc + ta)) * Cc + h * 64 + d] =
                __float2bfloat16(oa[j][r] / la[r]);
            const int tb = ta + 16;
            aout[((size_t)(b * Tc + tb)) * Cc + h * 64 + d] =
                __float2bfloat16(ob[j][r] / lb[r]);
        }
    }
}

extern "C" void kernel_launch(void* const* d_in, const int* in_sizes, int n_in,
                              void* d_out, int out_size, void* d_ws, size_t ws_size,
                              hipStream_t stream) {
    const float* x = nullptr;
    const float* w_qkv = nullptr;
    const float* w_proj = nullptr;
    for (int i = 0; i < n_in; i++) {
        if (in_sizes[i] == 4194304) x = (const float*)d_in[i];
        else if (in_sizes[i] == 3145728) w_qkv = (const float*)d_in[i];
        else if (in_sizes[i] == 1048576) w_proj = (const float*)d_in[i];
    }
    float* out = (float*)d_out;

    __hip_bfloat16* qkv = (__hip_bfloat16*)d_ws;        // q[4M] k[4M] v[4M]
    __hip_bfloat16* vbuf = qkv + 2 * QKV_STRIDE;        // v slot; becomes ao
    __hip_bfloat16* vt = qkv + 3 * QKV_STRIDE;          // 4M elems
    __hip_bfloat16* ao = vbuf;                          // attn out over dead v

    // split-K accumulators: after qkv+vt (8*QKV_STRIDE bytes = 32MB offset)
    const size_t ACC_OFF = 8 * QKV_STRIDE;              // bytes
    const size_t N_O = (size_t)Bc * Tc * Cc;            // 4194304 f32
    const size_t N_L = (size_t)Bc * Tc * Hc;            // 65536 f32
    const size_t NEED = ACC_OFF + (N_O + N_L) * sizeof(float);

    gemm_qkv<<<dim3(4096 / 128, 3072 / 128), 256, 0, stream>>>(x, w_qkv, qkv);
    transpose_v<<<dim3(Tc / 64, Hc, Bc), 256, 0, stream>>>(vbuf, vt);

    if (ws_size >= NEED) {
        float* accO = (float*)((char*)d_ws + ACC_OFF);
        float* accL = accO + N_O;
        const int n4 = (int)((N_O + N_L) / 4);          // 1064960 float4 groups
        zero_acc<<<dim3((n4 + 255) / 256), 256, 0, stream>>>(accO, n4);
        attn_split<<<dim3(40, 32), 256, 0, stream>>>(qkv, vt, accO, accL);
        attn_norm<<<dim3((Bc * Tc * Cc / 4) / 256), 256, 0, stream>>>(accO, accL, ao);
    } else {
        attn_kernel<<<dim3(Tc / 128, Hc, Bc), 256, 0, stream>>>(qkv, vt, ao);
    }

    gemm_proj<<<dim3(4096 / 128, 1024 / 64), 256, 0, stream>>>(ao, w_proj, out);
}

// Round 5
// 246.012 us; speedup vs baseline: 1.0889x; 1.0287x over previous
//
#include <hip/hip_runtime.h>
#include <hip/hip_bf16.h>

// ROUND 14: pure-bf16 GEMMs via one-time input conversion.
// R13 post-mortem: attn now 97us (latency-bound plateau); the top kernel is
// gemm_qkv (~100us, MfmaUtil 2.8%, 6.3M bank conflicts) because it stages
// f32 tiles and repacks to bf16 every K-step (64 cvt per 16 MFMA/wave).
// Fix: convert x/w_qkv/w_proj to bf16 once (~8us), then both GEMMs use the
// proven gemm_proj A-side pattern on BOTH operands: gl2lds16 of bf16 +
// direct bf16x8 LDS reads, zero cvt in the loop, LDS 32->16KB.
// Workspace overlays keep NEED identical: xb/wb_qkv live in the accO region
// (dead before zero_acc); wb_proj lives in the dead q region after attn.
// attn_split/norm/transpose unchanged from R13. Full f32 fallback kept.

typedef __attribute__((ext_vector_type(8))) short bf16x8;
typedef __attribute__((ext_vector_type(4))) short bf16x4;
typedef __attribute__((ext_vector_type(4))) float floatx4;

#define MFMA16(a, b, c) __builtin_amdgcn_mfma_f32_16x16x32_bf16((a), (b), (c), 0, 0, 0)

#if __has_builtin(__builtin_amdgcn_exp2f)
#define EXP2F(x) __builtin_amdgcn_exp2f(x)
#else
#define EXP2F(x) exp2f(x)
#endif

static constexpr int Bc = 2, Tc = 2048, Cc = 1024, Hc = 16, Dc = 64;
static constexpr size_t QKV_STRIDE = (size_t)Bc * Hc * Tc * Dc; // 4194304
static constexpr float KSL2E = 0.125f * 1.44269504088896f; // scale * log2(e)

__device__ __forceinline__ bf16x8 load8(const __hip_bfloat16* p) {
    return *(const bf16x8*)p;
}

__device__ __forceinline__ bf16x8 load8_lds(const __hip_bfloat16* p) {
    const bf16x4 lo = *(const bf16x4*)p;
    const bf16x4 hi = *(const bf16x4*)(p + 4);
    bf16x8 r;
    r[0] = lo[0]; r[1] = lo[1]; r[2] = lo[2]; r[3] = lo[3];
    r[4] = hi[0]; r[5] = hi[1]; r[6] = hi[2]; r[7] = hi[3];
    return r;
}

__device__ __forceinline__ short f2b(float x) {
    union { __hip_bfloat16 h; short s; } u;
    u.h = __float2bfloat16(x);
    return u.s;
}

__device__ __forceinline__ bf16x8 pack8(floatx4 a, floatx4 b) {
    bf16x8 r;
    r[0] = f2b(a[0]); r[1] = f2b(a[1]); r[2] = f2b(a[2]); r[3] = f2b(a[3]);
    r[4] = f2b(b[0]); r[5] = f2b(b[1]); r[6] = f2b(b[2]); r[7] = f2b(b[3]);
    return r;
}

__device__ __forceinline__ void gl2lds16(const void* g, void* l) {
    __builtin_amdgcn_global_load_lds(
        (const __attribute__((address_space(1))) void*)g,
        (__attribute__((address_space(3))) void*)l, 16, 0, 0);
}

// ================= f32 -> bf16 bulk convert (8 elems/thread) ================
__global__ __launch_bounds__(256) void cvt_bf16(
    const float* __restrict__ in, __hip_bfloat16* __restrict__ out, int n8) {
    const int i = blockIdx.x * 256 + threadIdx.x;
    if (i < n8) {
        const floatx4 a = *(const floatx4*)&in[(size_t)i * 8];
        const floatx4 b = *(const floatx4*)&in[(size_t)i * 8 + 4];
        *(bf16x8*)&out[(size_t)i * 8] = pack8(a, b);
    }
}

// ================= GEMM1 bf16: qkv = xb @ wb^T (128x128, BK=32) =============
__global__ __launch_bounds__(256) void gemm_qkv_bf16(
    const __hip_bfloat16* __restrict__ A,
    const __hip_bfloat16* __restrict__ W,
    __hip_bfloat16* __restrict__ qkv) {
    __shared__ __hip_bfloat16 As16[128 * 32];
    __shared__ __hip_bfloat16 Bs16[128 * 32];
    const int K = Cc;
    const int lane = threadIdx.x & 63;
    const int wave = threadIdx.x >> 6;
    const int waveM = wave >> 1, waveN = wave & 1;
    const int mBase = blockIdx.x * 128;
    const int nBase = blockIdx.y * 128;
    const int idx16 = lane & 15;
    const int quad = lane >> 4;
    const int aRow = lane >> 2, aPos = lane & 3;   // 16 rows x 16B per gl2lds

    floatx4 acc[4][4] = {};

    for (int k0 = 0; k0 < K; k0 += 32) {
        __syncthreads();
#pragma unroll
        for (int s = 0; s < 2; s++) {
            const int r0 = wave * 32 + s * 16;
            const int row = r0 + aRow;
            const int cg = aPos ^ (row & 3);
            gl2lds16(A + (size_t)(mBase + row) * K + k0 + cg * 8, &As16[r0 * 32]);
            gl2lds16(W + (size_t)(nBase + row) * K + k0 + cg * 8, &Bs16[r0 * 32]);
        }
        __syncthreads();

        bf16x8 af[4], bfr[4];
#pragma unroll
        for (int i = 0; i < 4; i++) {
            const int rr = waveM * 64 + i * 16 + idx16;
            af[i] = *(const bf16x8*)&As16[rr * 32 + ((quad ^ (rr & 3)) * 8)];
        }
#pragma unroll
        for (int j = 0; j < 4; j++) {
            const int rr = waveN * 64 + j * 16 + idx16;
            bfr[j] = *(const bf16x8*)&Bs16[rr * 32 + ((quad ^ (rr & 3)) * 8)];
        }
#pragma unroll
        for (int i = 0; i < 4; i++)
#pragma unroll
            for (int j = 0; j < 4; j++)
                acc[i][j] = MFMA16(af[i], bfr[j], acc[i][j]);
    }

#pragma unroll
    for (int i = 0; i < 4; i++) {
#pragma unroll
        for (int j = 0; j < 4; j++) {
            const int n = nBase + waveN * 64 + j * 16 + idx16;
            const int part = n >> 10;
            const int rem = n & 1023;
            const int h = rem >> 6, d = rem & 63;
#pragma unroll
            for (int r = 0; r < 4; r++) {
                const int m = mBase + waveM * 64 + i * 16 + quad * 4 + r;
                const int bb = m >> 11, t = m & 2047;
                const size_t o = (size_t)part * QKV_STRIDE +
                                 (((size_t)(bb * Hc + h)) * Tc + t) * Dc + d;
                qkv[o] = __float2bfloat16(acc[i][j][r]);
            }
        }
    }
}

// ================= GEMM2 bf16: out(f32) = ao @ wbp^T (128x64, BK=32) ========
__global__ __launch_bounds__(256) void gemm_proj_bf16(
    const __hip_bfloat16* __restrict__ A,
    const __hip_bfloat16* __restrict__ W,
    float* __restrict__ out) {
    __shared__ __hip_bfloat16 As16[128 * 32];
    __shared__ __hip_bfloat16 Bs16[64 * 32];
    const int K = Cc;
    const int lane = threadIdx.x & 63;
    const int wave = threadIdx.x >> 6;
    const int waveM = wave >> 1, waveN = wave & 1;
    const int mBase = blockIdx.x * 128;
    const int nBase = blockIdx.y * 64;
    const int idx16 = lane & 15;
    const int quad = lane >> 4;
    const int aRow = lane >> 2, aPos = lane & 3;

    floatx4 acc[4][2] = {};

    for (int k0 = 0; k0 < K; k0 += 32) {
        __syncthreads();
#pragma unroll
        for (int s = 0; s < 2; s++) {
            const int r0 = wave * 32 + s * 16;
            const int row = r0 + aRow;
            const int cg = aPos ^ (row & 3);
            gl2lds16(A + (size_t)(mBase + row) * K + k0 + cg * 8, &As16[r0 * 32]);
        }
        {
            const int r0 = wave * 16;
            const int row = r0 + aRow;
            const int cg = aPos ^ (row & 3);
            gl2lds16(W + (size_t)(nBase + row) * K + k0 + cg * 8, &Bs16[r0 * 32]);
        }
        __syncthreads();

        bf16x8 af[4], bfr[2];
#pragma unroll
        for (int i = 0; i < 4; i++) {
            const int rr = waveM * 64 + i * 16 + idx16;
            af[i] = *(const bf16x8*)&As16[rr * 32 + ((quad ^ (rr & 3)) * 8)];
        }
#pragma unroll
        for (int j = 0; j < 2; j++) {
            const int rr = waveN * 32 + j * 16 + idx16;
            bfr[j] = *(const bf16x8*)&Bs16[rr * 32 + ((quad ^ (rr & 3)) * 8)];
        }
#pragma unroll
        for (int i = 0; i < 4; i++)
#pragma unroll
            for (int j = 0; j < 2; j++)
                acc[i][j] = MFMA16(af[i], bfr[j], acc[i][j]);
    }

#pragma unroll
    for (int i = 0; i < 4; i++) {
#pragma unroll
        for (int j = 0; j < 2; j++) {
            const int n = nBase + waveN * 32 + j * 16 + idx16;
#pragma unroll
            for (int r = 0; r < 4; r++) {
                const int m = mBase + waveM * 64 + i * 16 + quad * 4 + r;
                out[(size_t)m * Cc + n] = acc[i][j][r];
            }
        }
    }
}

// ================= V transpose (unchanged): [b,h,t,d] -> [b,h,d,t] ==========
__global__ __launch_bounds__(256) void transpose_v(
    const __hip_bfloat16* __restrict__ v,
    __hip_bfloat16* __restrict__ vt) {
    __shared__ unsigned short tile[64][65];
    const int t0 = blockIdx.x * 64;
    const int h = blockIdx.y, b = blockIdx.z;
    const size_t base = ((size_t)(b * Hc + h)) * Tc * Dc;
    const unsigned short* vp = (const unsigned short*)v + base;
    unsigned short* vtp = (unsigned short*)vt + base;

    for (int e = threadIdx.x; e < 4096; e += 256) {
        const int tl = e >> 6, d = e & 63;
        tile[tl][d] = vp[(size_t)(t0 + tl) * Dc + d];
    }
    __syncthreads();
    for (int e = threadIdx.x; e < 4096; e += 256) {
        const int d = e >> 6, tl = e & 63;
        vtp[(size_t)d * Tc + t0 + tl] = tile[tl][d];
    }
}

// ================= zero accumulators ========================================
__global__ __launch_bounds__(256) void zero_acc(float* __restrict__ p, int n4) {
    const int i = blockIdx.x * 256 + threadIdx.x;
    if (i < n4) {
        floatx4 z = {0.f, 0.f, 0.f, 0.f};
        *(floatx4*)&p[(size_t)i * 4] = z;
    }
}

// ================= Flash attention (R13): split-K, 4 units / block ==========
__global__ __launch_bounds__(256) void attn_split(
    const __hip_bfloat16* __restrict__ qkv,
    const __hip_bfloat16* __restrict__ vt,
    float* __restrict__ accO,
    float* __restrict__ accL) {
    __shared__ __hip_bfloat16 lds_p[4][2][16][72];  // per-wave slab

    const int lane = threadIdx.x & 63;
    const int wave = threadIdx.x >> 6;
    const int col = lane & 15;
    const int quad = lane >> 4;

    const int g = blockIdx.x * 4 + wave;         // 0..159
    const int u = 159 - g;                       // heavy units first
    int w, s;
    if (u < 16)      { w = u;                 s = 0; }
    else if (u < 48) { const int q = u - 16;  w = 16 + (q >> 1); s = q & 1; }
    else if (u < 96) { const int q = u - 48;  w = 32 + q / 3;    s = q % 3; }
    else             { const int q = u - 96;  w = 48 + (q >> 2); s = q & 3; }

    const int bh = blockIdx.y;
    const int h = bh & 15, b = bh >> 4;
    const int qBase = w * 32;
    const int nt = ((qBase + 31) >> 6) + 1;      // total K-tiles this chunk
    const int kt0 = s * 8;
    const int ktEnd = min(nt, kt0 + 8);

    const size_t headOff = ((size_t)(b * Hc + h)) * Tc * Dc;
    const __hip_bfloat16* qp = qkv + headOff;
    const __hip_bfloat16* kp = qkv + QKV_STRIDE + headOff;
    const __hip_bfloat16* vtp = vt + headOff;    // [d][t] within head

    const int qrowA = qBase + col;               // frag A rows
    const int qrowB = qrowA + 16;                // frag B rows
    bf16x8 qfa[2], qfb[2];
    qfa[0] = load8(qp + (size_t)qrowA * Dc + quad * 8);
    qfa[1] = load8(qp + (size_t)qrowA * Dc + 32 + quad * 8);
    qfb[0] = load8(qp + (size_t)qrowB * Dc + quad * 8);
    qfb[1] = load8(qp + (size_t)qrowB * Dc + 32 + quad * 8);

    floatx4 oa[4] = {}, ob[4] = {};
    float la[4] = {0.f, 0.f, 0.f, 0.f}, lb[4] = {0.f, 0.f, 0.f, 0.f};
    const int q0a = qBase + quad * 4;
    const int q0b = q0a + 16;

    for (int kt = kt0; kt < ktEnd; kt++) {
        const int keyBase = kt * 64;

        bf16x8 kc0[4], kc1[4], vc0[4], vc1[4];
#pragma unroll
        for (int j = 0; j < 4; j++) {
            const int key = keyBase + j * 16 + col;
            kc0[j] = load8(kp + (size_t)key * Dc + quad * 8);
            kc1[j] = load8(kp + (size_t)key * Dc + 32 + quad * 8);
        }
#pragma unroll
        for (int j = 0; j < 4; j++) {
            const int d = j * 16 + col;
            vc0[j] = load8(vtp + (size_t)d * Tc + keyBase + quad * 8);
            vc1[j] = load8(vtp + (size_t)d * Tc + keyBase + 32 + quad * 8);
        }

        floatx4 sa[4], sb[4];
#pragma unroll
        for (int j = 0; j < 4; j++) {
            floatx4 a0 = {0.f, 0.f, 0.f, 0.f};
            a0 = MFMA16(qfa[0], kc0[j], a0);
            sa[j] = MFMA16(qfa[1], kc1[j], a0);
            floatx4 b0 = {0.f, 0.f, 0.f, 0.f};
            b0 = MFMA16(qfb[0], kc0[j], b0);
            sb[j] = MFMA16(qfb[1], kc1[j], b0);
        }

#pragma unroll
        for (int j = 0; j < 4; j++) {
            const int key = keyBase + j * 16 + col;
#pragma unroll
            for (int r = 0; r < 4; r++) {
                float pa = EXP2F(sa[j][r] * KSL2E);
                pa = (key > q0a + r) ? 0.f : pa;
                la[r] += pa;
                lds_p[wave][0][quad * 4 + r][j * 16 + col] = __float2bfloat16(pa);
                float pb = EXP2F(sb[j][r] * KSL2E);
                pb = (key > q0b + r) ? 0.f : pb;
                lb[r] += pb;
                lds_p[wave][1][quad * 4 + r][j * 16 + col] = __float2bfloat16(pb);
            }
        }

        const bf16x8 pa0 = load8_lds(&lds_p[wave][0][col][quad * 8]);
        const bf16x8 pa1 = load8_lds(&lds_p[wave][0][col][32 + quad * 8]);
        const bf16x8 pb0 = load8_lds(&lds_p[wave][1][col][quad * 8]);
        const bf16x8 pb1 = load8_lds(&lds_p[wave][1][col][32 + quad * 8]);
#pragma unroll
        for (int j = 0; j < 4; j++) {
            oa[j] = MFMA16(pa0, vc0[j], oa[j]);
            oa[j] = MFMA16(pa1, vc1[j], oa[j]);
            ob[j] = MFMA16(pb0, vc0[j], ob[j]);
            ob[j] = MFMA16(pb1, vc1[j], ob[j]);
        }
    }

#pragma unroll
    for (int off = 1; off < 16; off <<= 1)
#pragma unroll
        for (int r = 0; r < 4; r++) {
            la[r] += __shfl_xor(la[r], off, 64);
            lb[r] += __shfl_xor(lb[r], off, 64);
        }

#pragma unroll
    for (int j = 0; j < 4; j++) {
        const int d = j * 16 + col;
#pragma unroll
        for (int r = 0; r < 4; r++) {
            const int ta = q0a + r;
            atomicAdd(&accO[((size_t)(b * Tc + ta)) * Cc + h * 64 + d], oa[j][r]);
            const int tb = q0b + r;
            atomicAdd(&accO[((size_t)(b * Tc + tb)) * Cc + h * 64 + d], ob[j][r]);
        }
    }
    if (col == 0) {
#pragma unroll
        for (int r = 0; r < 4; r++) {
            atomicAdd(&accL[((size_t)(b * Tc + q0a + r)) * Hc + h], la[r]);
            atomicAdd(&accL[((size_t)(b * Tc + q0b + r)) * Hc + h], lb[r]);
        }
    }
}

// ================= normalize: ao(bf16) = accO / accL ========================
__global__ __launch_bounds__(256) void attn_norm(
    const float* __restrict__ accO,
    const float* __restrict__ accL,
    __hip_bfloat16* __restrict__ ao) {
    const int idx = blockIdx.x * 256 + threadIdx.x;  // 1M threads, 4 elems each
    const int m = idx >> 8;
    const int c4 = (idx & 255) << 2;
    const floatx4 o = *(const floatx4*)&accO[(size_t)m * Cc + c4];
    const float inv = 1.0f / accL[(size_t)m * Hc + (c4 >> 6)];
    bf16x4 r;
    r[0] = f2b(o[0] * inv); r[1] = f2b(o[1] * inv);
    r[2] = f2b(o[2] * inv); r[3] = f2b(o[3] * inv);
    *(bf16x4*)&ao[(size_t)m * Cc + c4] = r;
}

// ======== Fallback path (R10/R13 f32-staging kernels), used if ws small =====
__global__ __launch_bounds__(256) void gemm_qkv(
    const float* __restrict__ A,
    const float* __restrict__ W,
    __hip_bfloat16* __restrict__ qkv) {
    __shared__ float As[128 * 32];
    __shared__ float Bs[128 * 32];
    const int K = Cc;
    const int lane = threadIdx.x & 63;
    const int wave = threadIdx.x >> 6;
    const int waveM = wave >> 1, waveN = wave & 1;
    const int mBase = blockIdx.x * 128;
    const int nBase = blockIdx.y * 128;
    const int idx16 = lane & 15;
    const int quad = lane >> 4;
    const int ldRow = lane >> 3;
    const int ldPos = lane & 7;

    floatx4 acc[4][4] = {};

    for (int k0 = 0; k0 < K; k0 += 32) {
        __syncthreads();
#pragma unroll
        for (int s = 0; s < 4; s++) {
            const int r0 = wave * 32 + s * 8;
            const int row = r0 + ldRow;
            const int cg = ldPos ^ (row & 7);
            gl2lds16(A + (size_t)(mBase + row) * K + k0 + cg * 4, &As[r0 * 32]);
            gl2lds16(W + (size_t)(nBase + row) * K + k0 + cg * 4, &Bs[r0 * 32]);
        }
        __syncthreads();

        bf16x8 af[4], bfr[4];
#pragma unroll
        for (int i = 0; i < 4; i++) {
            const int rr = waveM * 64 + i * 16 + idx16;
            const floatx4 a0 = *(const floatx4*)&As[rr * 32 + (((quad * 2) ^ (rr & 7)) * 4)];
            const floatx4 a1 = *(const floatx4*)&As[rr * 32 + (((quad * 2 + 1) ^ (rr & 7)) * 4)];
            af[i] = pack8(a0, a1);
        }
#pragma unroll
        for (int j = 0; j < 4; j++) {
            const int rr = waveN * 64 + j * 16 + idx16;
            const floatx4 b0 = *(const floatx4*)&Bs[rr * 32 + (((quad * 2) ^ (rr & 7)) * 4)];
            const floatx4 b1 = *(const floatx4*)&Bs[rr * 32 + (((quad * 2 + 1) ^ (rr & 7)) * 4)];
            bfr[j] = pack8(b0, b1);
        }
#pragma unroll
        for (int i = 0; i < 4; i++)
#pragma unroll
            for (int j = 0; j < 4; j++)
                acc[i][j] = MFMA16(af[i], bfr[j], acc[i][j]);
    }

#pragma unroll
    for (int i = 0; i < 4; i++) {
#pragma unroll
        for (int j = 0; j < 4; j++) {
            const int n = nBase + waveN * 64 + j * 16 + idx16;
            const int part = n >> 10;
            const int rem = n & 1023;
            const int h = rem >> 6, d = rem & 63;
#pragma unroll
            for (int r = 0; r < 4; r++) {
                const int m = mBase + waveM * 64 + i * 16 + quad * 4 + r;
                const int bb = m >> 11, t = m & 2047;
                const size_t o = (size_t)part * QKV_STRIDE +
                                 (((size_t)(bb * Hc + h)) * Tc + t) * Dc + d;
                qkv[o] = __float2bfloat16(acc[i][j][r]);
            }
        }
    }
}

__global__ __launch_bounds__(256) void gemm_proj(
    const __hip_bfloat16* __restrict__ A,
    const float* __restrict__ W,
    float* __restrict__ out) {
    __shared__ __hip_bfloat16 As16[128 * 32];
    __shared__ float Ws[64 * 32];
    const int K = Cc;
    const int lane = threadIdx.x & 63;
    const int wave = threadIdx.x >> 6;
    const int waveM = wave >> 1, waveN = wave & 1;
    const int mBase = blockIdx.x * 128;
    const int nBase = blockIdx.y * 64;
    const int idx16 = lane & 15;
    const int quad = lane >> 4;
    const int aRow = lane >> 2, aPos = lane & 3;
    const int wRow = lane >> 3, wPos = lane & 7;

    floatx4 acc[4][2] = {};

    for (int k0 = 0; k0 < K; k0 += 32) {
        __syncthreads();
#pragma unroll
        for (int s = 0; s < 2; s++) {
            {
                const int r0 = wave * 32 + s * 16;
                const int row = r0 + aRow;
                const int cg = aPos ^ (row & 3);
                gl2lds16(A + (size_t)(mBase + row) * K + k0 + cg * 8, &As16[r0 * 32]);
            }
            {
                const int r0 = wave * 16 + s * 8;
                const int row = r0 + wRow;
                const int cg = wPos ^ (row & 7);
                gl2lds16(W + (size_t)(nBase + row) * K + k0 + cg * 4, &Ws[r0 * 32]);
            }
        }
        __syncthreads();

        bf16x8 af[4], bfr[2];
#pragma unroll
        for (int i = 0; i < 4; i++) {
            const int rr = waveM * 64 + i * 16 + idx16;
            af[i] = *(const bf16x8*)&As16[rr * 32 + ((quad ^ (rr & 3)) * 8)];
        }
#pragma unroll
        for (int j = 0; j < 2; j++) {
            const int rr = waveN * 32 + j * 16 + idx16;
            const floatx4 b0 = *(const floatx4*)&Ws[rr * 32 + (((quad * 2) ^ (rr & 7)) * 4)];
            const floatx4 b1 = *(const floatx4*)&Ws[rr * 32 + (((quad * 2 + 1) ^ (rr & 7)) * 4)];
            bfr[j] = pack8(b0, b1);
        }
#pragma unroll
        for (int i = 0; i < 4; i++)
#pragma unroll
            for (int j = 0; j < 2; j++)
                acc[i][j] = MFMA16(af[i], bfr[j], acc[i][j]);
    }

#pragma unroll
    for (int i = 0; i < 4; i++) {
#pragma unroll
        for (int j = 0; j < 2; j++) {
            const int n = nBase + waveN * 32 + j * 16 + idx16;
#pragma unroll
            for (int r = 0; r < 4; r++) {
                const int m = mBase + waveM * 64 + i * 16 + quad * 4 + r;
                out[(size_t)m * Cc + n] = acc[i][j][r];
            }
        }
    }
}

__global__ __launch_bounds__(256) void attn_kernel(
    const __hip_bfloat16* __restrict__ qkv,
    const __hip_bfloat16* __restrict__ vt,
    __hip_bfloat16* __restrict__ aout) {
    __shared__ __hip_bfloat16 lds_p[4][2][16][72];

    const int lane = threadIdx.x & 63;
    const int wave = threadIdx.x >> 6;
    const int col = lane & 15;
    const int quad = lane >> 4;
    const int qt = (gridDim.x - 1) - blockIdx.x;
    const int h = blockIdx.y;
    const int b = blockIdx.z;
    const int qBase = qt * 128;

    const size_t headOff = ((size_t)(b * Hc + h)) * Tc * Dc;
    const __hip_bfloat16* qp = qkv + headOff;
    const __hip_bfloat16* kp = qkv + QKV_STRIDE + headOff;
    const __hip_bfloat16* vtp = vt + headOff;

    const int qrowA = qBase + wave * 32 + col;
    const int qrowB = qrowA + 16;
    bf16x8 qfa[2], qfb[2];
    qfa[0] = load8(qp + (size_t)qrowA * Dc + quad * 8);
    qfa[1] = load8(qp + (size_t)qrowA * Dc + 32 + quad * 8);
    qfb[0] = load8(qp + (size_t)qrowB * Dc + quad * 8);
    qfb[1] = load8(qp + (size_t)qrowB * Dc + 32 + quad * 8);

    floatx4 oa[4] = {}, ob[4] = {};
    float la[4] = {0.f, 0.f, 0.f, 0.f}, lb[4] = {0.f, 0.f, 0.f, 0.f};
    const int q0a = qBase + wave * 32 + quad * 4;
    const int q0b = q0a + 16;
    const int qtw = (qBase + wave * 32 + 31) >> 6;

    for (int kt = 0; kt <= qtw; kt++) {
        const int keyBase = kt * 64;
        bf16x8 kc0[4], kc1[4], vc0[4], vc1[4];
#pragma unroll
        for (int j = 0; j < 4; j++) {
            const int key = keyBase + j * 16 + col;
            kc0[j] = load8(kp + (size_t)key * Dc + quad * 8);
            kc1[j] = load8(kp + (size_t)key * Dc + 32 + quad * 8);
        }
#pragma unroll
        for (int j = 0; j < 4; j++) {
            const int d = j * 16 + col;
            vc0[j] = load8(vtp + (size_t)d * Tc + keyBase + quad * 8);
            vc1[j] = load8(vtp + (size_t)d * Tc + keyBase + 32 + quad * 8);
        }

        floatx4 sa[4], sb[4];
#pragma unroll
        for (int j = 0; j < 4; j++) {
            floatx4 a0 = {0.f, 0.f, 0.f, 0.f};
            a0 = MFMA16(qfa[0], kc0[j], a0);
            sa[j] = MFMA16(qfa[1], kc1[j], a0);
            floatx4 b0 = {0.f, 0.f, 0.f, 0.f};
            b0 = MFMA16(qfb[0], kc0[j], b0);
            sb[j] = MFMA16(qfb[1], kc1[j], b0);
        }

#pragma unroll
        for (int j = 0; j < 4; j++) {
            const int key = keyBase + j * 16 + col;
#pragma unroll
            for (int r = 0; r < 4; r++) {
                float pa = EXP2F(sa[j][r] * KSL2E);
                pa = (key > q0a + r) ? 0.f : pa;
                la[r] += pa;
                lds_p[wave][0][quad * 4 + r][j * 16 + col] = __float2bfloat16(pa);
                float pb = EXP2F(sb[j][r] * KSL2E);
                pb = (key > q0b + r) ? 0.f : pb;
                lb[r] += pb;
                lds_p[wave][1][quad * 4 + r][j * 16 + col] = __float2bfloat16(pb);
            }
        }

        const bf16x8 pa0 = load8_lds(&lds_p[wave][0][col][quad * 8]);
        const bf16x8 pa1 = load8_lds(&lds_p[wave][0][col][32 + quad * 8]);
        const bf16x8 pb0 = load8_lds(&lds_p[wave][1][col][quad * 8]);
        const bf16x8 pb1 = load8_lds(&lds_p[wave][1][col][32 + quad * 8]);
#pragma unroll
        for (int j = 0; j < 4; j++) {
            oa[j] = MFMA16(pa0, vc0[j], oa[j]);
            oa[j] = MFMA16(pa1, vc1[j], oa[j]);
            ob[j] = MFMA16(pb0, vc0[j], ob[j]);
            ob[j] = MFMA16(pb1, vc1[j], ob[j]);
        }
    }

#pragma unroll
    for (int off = 1; off < 16; off <<= 1)
#pragma unroll
        for (int r = 0; r < 4; r++) {
            la[r] += __shfl_xor(la[r], off, 64);
            lb[r] += __shfl_xor(lb[r], off, 64);
        }

#pragma unroll
    for (int j = 0; j < 4; j++) {
        const int d = j * 16 + col;
#pragma unroll
        for (int r = 0; r < 4; r++) {
            const int ta = qBase + wave * 32 + quad * 4 + r;
            aout[((size_t)(b * Tc + ta)) * Cc + h * 64 + d] =
                __float2bfloat16(oa[j][r] / la[r]);
            const int tb = ta + 16;
            aout[((size_t)(b * Tc + tb)) * Cc + h * 64 + d] =
                __float2bfloat16(ob[j][r] / lb[r]);
        }
    }
}

extern "C" void kernel_launch(void* const* d_in, const int* in_sizes, int n_in,
                              void* d_out, int out_size, void* d_ws, size_t ws_size,
                              hipStream_t stream) {
    const float* x = nullptr;
    const float* w_qkv = nullptr;
    const float* w_proj = nullptr;
    for (int i = 0; i < n_in; i++) {
        if (in_sizes[i] == 4194304) x = (const float*)d_in[i];
        else if (in_sizes[i] == 3145728) w_qkv = (const float*)d_in[i];
        else if (in_sizes[i] == 1048576) w_proj = (const float*)d_in[i];
    }
    float* out = (float*)d_out;

    __hip_bfloat16* qkv = (__hip_bfloat16*)d_ws;        // q[4M] k[4M] v[4M]
    __hip_bfloat16* vbuf = qkv + 2 * QKV_STRIDE;        // v slot; becomes ao
    __hip_bfloat16* vt = qkv + 3 * QKV_STRIDE;          // 4M elems
    __hip_bfloat16* ao = vbuf;                          // attn out over dead v

    // accumulators after qkv+vt (8*QKV_STRIDE bytes = 32MB offset)
    const size_t ACC_OFF = 8 * QKV_STRIDE;              // bytes
    const size_t N_O = (size_t)Bc * Tc * Cc;            // 4194304 f32
    const size_t N_L = (size_t)Bc * Tc * Hc;            // 65536 f32
    const size_t NEED = ACC_OFF + (N_O + N_L) * sizeof(float);

    if (ws_size >= NEED) {
        float* accO = (float*)((char*)d_ws + ACC_OFF);
        float* accL = accO + N_O;
        // bf16 inputs OVERLAY the acc region (dead before zero_acc):
        __hip_bfloat16* xb = (__hip_bfloat16*)accO;          // 4M elems, 8MB
        __hip_bfloat16* wbq = xb + 4194304;                  // 3M elems, 6MB
        // w_proj bf16 goes into the q region AFTER attn (q dead by then):
        __hip_bfloat16* wbp = qkv;                           // 1M elems, 2MB

        cvt_bf16<<<dim3(4194304 / 8 / 256), 256, 0, stream>>>(x, xb, 4194304 / 8);
        cvt_bf16<<<dim3(3145728 / 8 / 256), 256, 0, stream>>>(w_qkv, wbq, 3145728 / 8);
        gemm_qkv_bf16<<<dim3(4096 / 128, 3072 / 128), 256, 0, stream>>>(xb, wbq, qkv);
        transpose_v<<<dim3(Tc / 64, Hc, Bc), 256, 0, stream>>>(vbuf, vt);

        const int n4 = (int)((N_O + N_L) / 4);
        zero_acc<<<dim3((n4 + 255) / 256), 256, 0, stream>>>(accO, n4);
        attn_split<<<dim3(40, 32), 256, 0, stream>>>(qkv, vt, accO, accL);
        attn_norm<<<dim3((Bc * Tc * Cc / 4) / 256), 256, 0, stream>>>(accO, accL, ao);

        cvt_bf16<<<dim3(1048576 / 8 / 256), 256, 0, stream>>>(w_proj, wbp, 1048576 / 8);
        gemm_proj_bf16<<<dim3(4096 / 128, 1024 / 64), 256, 0, stream>>>(ao, wbp, out);
    } else {
        gemm_qkv<<<dim3(4096 / 128, 3072 / 128), 256, 0, stream>>>(x, w_qkv, qkv);
        transpose_v<<<dim3(Tc / 64, Hc, Bc), 256, 0, stream>>>(vbuf, vt);
        attn_kernel<<<dim3(Tc / 128, Hc, Bc), 256, 0, stream>>>(qkv, vt, ao);
        gemm_proj<<<dim3(4096 / 128, 1024 / 64), 256, 0, stream>>>(ao, w_proj, out);
    }
}

// Round 6
// 208.410 us; speedup vs baseline: 1.2854x; 1.1804x over previous
//
#include <hip/hip_runtime.h>
#include <hip/hip_bf16.h>

// ROUND 15: LDS-staged double-buffered flash attention (replaces split-K).
// R14 post-mortem: attn_split stuck at 98us — per-tile latency is structural
// (16 scattered per-lane gathers/tile, 5x redundant K/V reads across chunks,
// 10.5M atomics). New attn_fa: block=(b,h,128q), 4 waves; K/Vt tiles staged
// to LDS via global_load_lds (4 coalesced 16B issues/thread/tile), shared by
// all 4 waves, double-buffered with the proven 2-barrier pattern (stage next
// tile at top of compute). Bank-conflict fix per rule #21: linear LDS dest +
// inverse-swizzled global source (chunk^=row&7) + swizzled ds_read -> 2-way.
// Split-K/atomics/zero/norm deleted; direct output like R10.
// GEMMs (bf16, R14) and transpose unchanged.

typedef __attribute__((ext_vector_type(8))) short bf16x8;
typedef __attribute__((ext_vector_type(4))) short bf16x4;
typedef __attribute__((ext_vector_type(4))) float floatx4;

#define MFMA16(a, b, c) __builtin_amdgcn_mfma_f32_16x16x32_bf16((a), (b), (c), 0, 0, 0)

#if __has_builtin(__builtin_amdgcn_exp2f)
#define EXP2F(x) __builtin_amdgcn_exp2f(x)
#else
#define EXP2F(x) exp2f(x)
#endif

static constexpr int Bc = 2, Tc = 2048, Cc = 1024, Hc = 16, Dc = 64;
static constexpr size_t QKV_STRIDE = (size_t)Bc * Hc * Tc * Dc; // 4194304
static constexpr float KSL2E = 0.125f * 1.44269504088896f; // scale * log2(e)

__device__ __forceinline__ bf16x8 load8(const __hip_bfloat16* p) {
    return *(const bf16x8*)p;
}

__device__ __forceinline__ bf16x8 load8_lds(const __hip_bfloat16* p) {
    const bf16x4 lo = *(const bf16x4*)p;
    const bf16x4 hi = *(const bf16x4*)(p + 4);
    bf16x8 r;
    r[0] = lo[0]; r[1] = lo[1]; r[2] = lo[2]; r[3] = lo[3];
    r[4] = hi[0]; r[5] = hi[1]; r[6] = hi[2]; r[7] = hi[3];
    return r;
}

__device__ __forceinline__ short f2b(float x) {
    union { __hip_bfloat16 h; short s; } u;
    u.h = __float2bfloat16(x);
    return u.s;
}

__device__ __forceinline__ bf16x8 pack8(floatx4 a, floatx4 b) {
    bf16x8 r;
    r[0] = f2b(a[0]); r[1] = f2b(a[1]); r[2] = f2b(a[2]); r[3] = f2b(a[3]);
    r[4] = f2b(b[0]); r[5] = f2b(b[1]); r[6] = f2b(b[2]); r[7] = f2b(b[3]);
    return r;
}

__device__ __forceinline__ void gl2lds16(const void* g, void* l) {
    __builtin_amdgcn_global_load_lds(
        (const __attribute__((address_space(1))) void*)g,
        (__attribute__((address_space(3))) void*)l, 16, 0, 0);
}

// ================= f32 -> bf16 bulk convert (8 elems/thread) ================
__global__ __launch_bounds__(256) void cvt_bf16(
    const float* __restrict__ in, __hip_bfloat16* __restrict__ out, int n8) {
    const int i = blockIdx.x * 256 + threadIdx.x;
    if (i < n8) {
        const floatx4 a = *(const floatx4*)&in[(size_t)i * 8];
        const floatx4 b = *(const floatx4*)&in[(size_t)i * 8 + 4];
        *(bf16x8*)&out[(size_t)i * 8] = pack8(a, b);
    }
}

// ================= GEMM1 bf16 (R14): qkv = xb @ wb^T ========================
__global__ __launch_bounds__(256) void gemm_qkv_bf16(
    const __hip_bfloat16* __restrict__ A,
    const __hip_bfloat16* __restrict__ W,
    __hip_bfloat16* __restrict__ qkv) {
    __shared__ __hip_bfloat16 As16[128 * 32];
    __shared__ __hip_bfloat16 Bs16[128 * 32];
    const int K = Cc;
    const int lane = threadIdx.x & 63;
    const int wave = threadIdx.x >> 6;
    const int waveM = wave >> 1, waveN = wave & 1;
    const int mBase = blockIdx.x * 128;
    const int nBase = blockIdx.y * 128;
    const int idx16 = lane & 15;
    const int quad = lane >> 4;
    const int aRow = lane >> 2, aPos = lane & 3;

    floatx4 acc[4][4] = {};

    for (int k0 = 0; k0 < K; k0 += 32) {
        __syncthreads();
#pragma unroll
        for (int s = 0; s < 2; s++) {
            const int r0 = wave * 32 + s * 16;
            const int row = r0 + aRow;
            const int cg = aPos ^ (row & 3);
            gl2lds16(A + (size_t)(mBase + row) * K + k0 + cg * 8, &As16[r0 * 32]);
            gl2lds16(W + (size_t)(nBase + row) * K + k0 + cg * 8, &Bs16[r0 * 32]);
        }
        __syncthreads();

        bf16x8 af[4], bfr[4];
#pragma unroll
        for (int i = 0; i < 4; i++) {
            const int rr = waveM * 64 + i * 16 + idx16;
            af[i] = *(const bf16x8*)&As16[rr * 32 + ((quad ^ (rr & 3)) * 8)];
        }
#pragma unroll
        for (int j = 0; j < 4; j++) {
            const int rr = waveN * 64 + j * 16 + idx16;
            bfr[j] = *(const bf16x8*)&Bs16[rr * 32 + ((quad ^ (rr & 3)) * 8)];
        }
#pragma unroll
        for (int i = 0; i < 4; i++)
#pragma unroll
            for (int j = 0; j < 4; j++)
                acc[i][j] = MFMA16(af[i], bfr[j], acc[i][j]);
    }

#pragma unroll
    for (int i = 0; i < 4; i++) {
#pragma unroll
        for (int j = 0; j < 4; j++) {
            const int n = nBase + waveN * 64 + j * 16 + idx16;
            const int part = n >> 10;
            const int rem = n & 1023;
            const int h = rem >> 6, d = rem & 63;
#pragma unroll
            for (int r = 0; r < 4; r++) {
                const int m = mBase + waveM * 64 + i * 16 + quad * 4 + r;
                const int bb = m >> 11, t = m & 2047;
                const size_t o = (size_t)part * QKV_STRIDE +
                                 (((size_t)(bb * Hc + h)) * Tc + t) * Dc + d;
                qkv[o] = __float2bfloat16(acc[i][j][r]);
            }
        }
    }
}

// ================= GEMM2 bf16 (R14): out(f32) = ao @ wbp^T ==================
__global__ __launch_bounds__(256) void gemm_proj_bf16(
    const __hip_bfloat16* __restrict__ A,
    const __hip_bfloat16* __restrict__ W,
    float* __restrict__ out) {
    __shared__ __hip_bfloat16 As16[128 * 32];
    __shared__ __hip_bfloat16 Bs16[64 * 32];
    const int K = Cc;
    const int lane = threadIdx.x & 63;
    const int wave = threadIdx.x >> 6;
    const int waveM = wave >> 1, waveN = wave & 1;
    const int mBase = blockIdx.x * 128;
    const int nBase = blockIdx.y * 64;
    const int idx16 = lane & 15;
    const int quad = lane >> 4;
    const int aRow = lane >> 2, aPos = lane & 3;

    floatx4 acc[4][2] = {};

    for (int k0 = 0; k0 < K; k0 += 32) {
        __syncthreads();
#pragma unroll
        for (int s = 0; s < 2; s++) {
            const int r0 = wave * 32 + s * 16;
            const int row = r0 + aRow;
            const int cg = aPos ^ (row & 3);
            gl2lds16(A + (size_t)(mBase + row) * K + k0 + cg * 8, &As16[r0 * 32]);
        }
        {
            const int r0 = wave * 16;
            const int row = r0 + aRow;
            const int cg = aPos ^ (row & 3);
            gl2lds16(W + (size_t)(nBase + row) * K + k0 + cg * 8, &Bs16[r0 * 32]);
        }
        __syncthreads();

        bf16x8 af[4], bfr[2];
#pragma unroll
        for (int i = 0; i < 4; i++) {
            const int rr = waveM * 64 + i * 16 + idx16;
            af[i] = *(const bf16x8*)&As16[rr * 32 + ((quad ^ (rr & 3)) * 8)];
        }
#pragma unroll
        for (int j = 0; j < 2; j++) {
            const int rr = waveN * 32 + j * 16 + idx16;
            bfr[j] = *(const bf16x8*)&Bs16[rr * 32 + ((quad ^ (rr & 3)) * 8)];
        }
#pragma unroll
        for (int i = 0; i < 4; i++)
#pragma unroll
            for (int j = 0; j < 2; j++)
                acc[i][j] = MFMA16(af[i], bfr[j], acc[i][j]);
    }

#pragma unroll
    for (int i = 0; i < 4; i++) {
#pragma unroll
        for (int j = 0; j < 2; j++) {
            const int n = nBase + waveN * 32 + j * 16 + idx16;
#pragma unroll
            for (int r = 0; r < 4; r++) {
                const int m = mBase + waveM * 64 + i * 16 + quad * 4 + r;
                out[(size_t)m * Cc + n] = acc[i][j][r];
            }
        }
    }
}

// ================= V transpose (unchanged): [b,h,t,d] -> [b,h,d,t] ==========
__global__ __launch_bounds__(256) void transpose_v(
    const __hip_bfloat16* __restrict__ v,
    __hip_bfloat16* __restrict__ vt) {
    __shared__ unsigned short tile[64][65];
    const int t0 = blockIdx.x * 64;
    const int h = blockIdx.y, b = blockIdx.z;
    const size_t base = ((size_t)(b * Hc + h)) * Tc * Dc;
    const unsigned short* vp = (const unsigned short*)v + base;
    unsigned short* vtp = (unsigned short*)vt + base;

    for (int e = threadIdx.x; e < 4096; e += 256) {
        const int tl = e >> 6, d = e & 63;
        tile[tl][d] = vp[(size_t)(t0 + tl) * Dc + d];
    }
    __syncthreads();
    for (int e = threadIdx.x; e < 4096; e += 256) {
        const int d = e >> 6, tl = e & 63;
        vtp[(size_t)d * Tc + t0 + tl] = tile[tl][d];
    }
}

// ================= Flash attention v7: LDS-staged, double-buffered ==========
// Block = (b, h, 128 q), 4 waves x 32 q. K-tile and Vt-tile (64x64 bf16 each)
// staged via global_load_lds into double buffers, shared by all 4 waves.
// LDS layout swizzle: 16B chunk c of row r stored at chunk c^(r&7) (linear
// dest, inverse-swizzled global src, swizzled read -> 2-way conflicts only).
// All waves loop nt = 2*qt+2 tiles (uniform barriers); causal mask zeroes
// out-of-range keys. Per-tile: stage(kt+1) at top of compute (overlap), two
// barriers. Direct bf16 output.
__global__ __launch_bounds__(256) void attn_fa(
    const __hip_bfloat16* __restrict__ qkv,
    const __hip_bfloat16* __restrict__ vt,
    __hip_bfloat16* __restrict__ aout) {
    __shared__ __hip_bfloat16 kbuf[2][64 * 64];   // 8KB each
    __shared__ __hip_bfloat16 vbuf2[2][64 * 64];  // 8KB each
    __shared__ __hip_bfloat16 lds_p[4][2][16][72];

    const int lane = threadIdx.x & 63;
    const int wave = threadIdx.x >> 6;
    const int col = lane & 15;
    const int quad = lane >> 4;
    const int qt = (gridDim.x - 1) - blockIdx.x;    // heavy blocks first
    const int h = blockIdx.y;
    const int b = blockIdx.z;
    const int qBase = qt * 128;
    const int nt = qt * 2 + 2;                      // K-tiles for this block

    const size_t headOff = ((size_t)(b * Hc + h)) * Tc * Dc;
    const __hip_bfloat16* qp = qkv + headOff;
    const __hip_bfloat16* kp = qkv + QKV_STRIDE + headOff;
    const __hip_bfloat16* vtp = vt + headOff;       // [d][t] within head

    const int qrowA = qBase + wave * 32 + col;      // frag A rows
    const int qrowB = qrowA + 16;                   // frag B rows
    bf16x8 qfa[2], qfb[2];
    qfa[0] = load8(qp + (size_t)qrowA * Dc + quad * 8);
    qfa[1] = load8(qp + (size_t)qrowA * Dc + 32 + quad * 8);
    qfb[0] = load8(qp + (size_t)qrowB * Dc + quad * 8);
    qfb[1] = load8(qp + (size_t)qrowB * Dc + 32 + quad * 8);

    floatx4 oa[4] = {}, ob[4] = {};
    float la[4] = {0.f, 0.f, 0.f, 0.f}, lb[4] = {0.f, 0.f, 0.f, 0.f};
    const int q0a = qBase + wave * 32 + quad * 4;
    const int q0b = q0a + 16;

    // stage tile kt into buffer buf: per wave 2x 1KB regions for K and Vt.
    // LDS dest is wave-uniform base + lane*16 (HW rule); the global source
    // chunk is inverse-swizzled: g = (lane&7) ^ (row&7).
    auto stage = [&](int kt, int buf) {
        const int keyBase = kt * 64;
#pragma unroll
        for (int s = 0; s < 2; s++) {
            const int blk = wave * 2 + s;            // 0..7 (8 rows each)
            const int row = blk * 8 + (lane >> 3);   // 0..63
            const int g = (lane & 7) ^ (row & 7);    // source 16B chunk
            gl2lds16(kp + (size_t)(keyBase + row) * Dc + g * 8,
                     &kbuf[buf][blk * 512]);
            gl2lds16(vtp + (size_t)row * Tc + keyBase + g * 8,
                     &vbuf2[buf][blk * 512]);
        }
    };

    stage(0, 0);
    int cur = 0;

    for (int kt = 0; kt < nt; kt++) {
        const int keyBase = kt * 64;
        __syncthreads();                    // buf[cur] staged (vmcnt drained)
        if (kt + 1 < nt) stage(kt + 1, cur ^ 1);   // prefetch overlaps compute

        // --- read K/Vt frags from swizzled LDS (2-way conflicts only) ---
        bf16x8 kc0[4], kc1[4], vc0[4], vc1[4];
#pragma unroll
        for (int j = 0; j < 4; j++) {
            const int kr = j * 16 + col;            // local key row
            const int m = kr & 7;
            kc0[j] = load8(&kbuf[cur][kr * 64 + ((quad * 8) ^ (m * 8))]);
            kc1[j] = load8(&kbuf[cur][kr * 64 + ((32 + quad * 8) ^ (m * 8))]);
            const int d = kr;                        // local d row (same form)
            vc0[j] = load8(&vbuf2[cur][d * 64 + ((quad * 8) ^ (m * 8))]);
            vc1[j] = load8(&vbuf2[cur][d * 64 + ((32 + quad * 8) ^ (m * 8))]);
        }

        // --- S = Q K^T for both q-frags ---
        floatx4 sa[4], sb[4];
#pragma unroll
        for (int j = 0; j < 4; j++) {
            floatx4 a0 = {0.f, 0.f, 0.f, 0.f};
            a0 = MFMA16(qfa[0], kc0[j], a0);
            sa[j] = MFMA16(qfa[1], kc1[j], a0);
            floatx4 b0 = {0.f, 0.f, 0.f, 0.f};
            b0 = MFMA16(qfb[0], kc0[j], b0);
            sb[j] = MFMA16(qfb[1], kc1[j], b0);
        }

        // --- P = exp2(s*KSL2E), branchless causal mask, per-lane l ---
#pragma unroll
        for (int j = 0; j < 4; j++) {
            const int key = keyBase + j * 16 + col;
#pragma unroll
            for (int r = 0; r < 4; r++) {
                float pa = EXP2F(sa[j][r] * KSL2E);
                pa = (key > q0a + r) ? 0.f : pa;
                la[r] += pa;
                lds_p[wave][0][quad * 4 + r][j * 16 + col] = __float2bfloat16(pa);
                float pb = EXP2F(sb[j][r] * KSL2E);
                pb = (key > q0b + r) ? 0.f : pb;
                lb[r] += pb;
                lds_p[wave][1][quad * 4 + r][j * 16 + col] = __float2bfloat16(pb);
            }
        }

        // --- O += P V (P A-frags from wave-private LDS; Vt from LDS) ---
        const bf16x8 pa0 = load8_lds(&lds_p[wave][0][col][quad * 8]);
        const bf16x8 pa1 = load8_lds(&lds_p[wave][0][col][32 + quad * 8]);
        const bf16x8 pb0 = load8_lds(&lds_p[wave][1][col][quad * 8]);
        const bf16x8 pb1 = load8_lds(&lds_p[wave][1][col][32 + quad * 8]);
#pragma unroll
        for (int j = 0; j < 4; j++) {
            oa[j] = MFMA16(pa0, vc0[j], oa[j]);
            oa[j] = MFMA16(pa1, vc1[j], oa[j]);
            ob[j] = MFMA16(pb0, vc0[j], ob[j]);
            ob[j] = MFMA16(pb1, vc1[j], ob[j]);
        }

        __syncthreads();                    // all waves done with buf[cur]
        cur ^= 1;
    }

    // --- reduce l across the 16 col-lanes of each quad group ---
#pragma unroll
    for (int off = 1; off < 16; off <<= 1)
#pragma unroll
        for (int r = 0; r < 4; r++) {
            la[r] += __shfl_xor(la[r], off, 64);
            lb[r] += __shfl_xor(lb[r], off, 64);
        }

#pragma unroll
    for (int j = 0; j < 4; j++) {
        const int d = j * 16 + col;
#pragma unroll
        for (int r = 0; r < 4; r++) {
            const int ta = qBase + wave * 32 + quad * 4 + r;
            aout[((size_t)(b * Tc + ta)) * Cc + h * 64 + d] =
                __float2bfloat16(oa[j][r] / la[r]);
            const int tb = ta + 16;
            aout[((size_t)(b * Tc + tb)) * Cc + h * 64 + d] =
                __float2bfloat16(ob[j][r] / lb[r]);
        }
    }
}

// ======== Fallback f32-staging GEMMs (used only if ws too small) ============
__global__ __launch_bounds__(256) void gemm_qkv(
    const float* __restrict__ A,
    const float* __restrict__ W,
    __hip_bfloat16* __restrict__ qkv) {
    __shared__ float As[128 * 32];
    __shared__ float Bs[128 * 32];
    const int K = Cc;
    const int lane = threadIdx.x & 63;
    const int wave = threadIdx.x >> 6;
    const int waveM = wave >> 1, waveN = wave & 1;
    const int mBase = blockIdx.x * 128;
    const int nBase = blockIdx.y * 128;
    const int idx16 = lane & 15;
    const int quad = lane >> 4;
    const int ldRow = lane >> 3;
    const int ldPos = lane & 7;

    floatx4 acc[4][4] = {};

    for (int k0 = 0; k0 < K; k0 += 32) {
        __syncthreads();
#pragma unroll
        for (int s = 0; s < 4; s++) {
            const int r0 = wave * 32 + s * 8;
            const int row = r0 + ldRow;
            const int cg = ldPos ^ (row & 7);
            gl2lds16(A + (size_t)(mBase + row) * K + k0 + cg * 4, &As[r0 * 32]);
            gl2lds16(W + (size_t)(nBase + row) * K + k0 + cg * 4, &Bs[r0 * 32]);
        }
        __syncthreads();

        bf16x8 af[4], bfr[4];
#pragma unroll
        for (int i = 0; i < 4; i++) {
            const int rr = waveM * 64 + i * 16 + idx16;
            const floatx4 a0 = *(const floatx4*)&As[rr * 32 + (((quad * 2) ^ (rr & 7)) * 4)];
            const floatx4 a1 = *(const floatx4*)&As[rr * 32 + (((quad * 2 + 1) ^ (rr & 7)) * 4)];
            af[i] = pack8(a0, a1);
        }
#pragma unroll
        for (int j = 0; j < 4; j++) {
            const int rr = waveN * 64 + j * 16 + idx16;
            const floatx4 b0 = *(const floatx4*)&Bs[rr * 32 + (((quad * 2) ^ (rr & 7)) * 4)];
            const floatx4 b1 = *(const floatx4*)&Bs[rr * 32 + (((quad * 2 + 1) ^ (rr & 7)) * 4)];
            bfr[j] = pack8(b0, b1);
        }
#pragma unroll
        for (int i = 0; i < 4; i++)
#pragma unroll
            for (int j = 0; j < 4; j++)
                acc[i][j] = MFMA16(af[i], bfr[j], acc[i][j]);
    }

#pragma unroll
    for (int i = 0; i < 4; i++) {
#pragma unroll
        for (int j = 0; j < 4; j++) {
            const int n = nBase + waveN * 64 + j * 16 + idx16;
            const int part = n >> 10;
            const int rem = n & 1023;
            const int h = rem >> 6, d = rem & 63;
#pragma unroll
            for (int r = 0; r < 4; r++) {
                const int m = mBase + waveM * 64 + i * 16 + quad * 4 + r;
                const int bb = m >> 11, t = m & 2047;
                const size_t o = (size_t)part * QKV_STRIDE +
                                 (((size_t)(bb * Hc + h)) * Tc + t) * Dc + d;
                qkv[o] = __float2bfloat16(acc[i][j][r]);
            }
        }
    }
}

__global__ __launch_bounds__(256) void gemm_proj(
    const __hip_bfloat16* __restrict__ A,
    const float* __restrict__ W,
    float* __restrict__ out) {
    __shared__ __hip_bfloat16 As16[128 * 32];
    __shared__ float Ws[64 * 32];
    const int K = Cc;
    const int lane = threadIdx.x & 63;
    const int wave = threadIdx.x >> 6;
    const int waveM = wave >> 1, waveN = wave & 1;
    const int mBase = blockIdx.x * 128;
    const int nBase = blockIdx.y * 64;
    const int idx16 = lane & 15;
    const int quad = lane >> 4;
    const int aRow = lane >> 2, aPos = lane & 3;
    const int wRow = lane >> 3, wPos = lane & 7;

    floatx4 acc[4][2] = {};

    for (int k0 = 0; k0 < K; k0 += 32) {
        __syncthreads();
#pragma unroll
        for (int s = 0; s < 2; s++) {
            {
                const int r0 = wave * 32 + s * 16;
                const int row = r0 + aRow;
                const int cg = aPos ^ (row & 3);
                gl2lds16(A + (size_t)(mBase + row) * K + k0 + cg * 8, &As16[r0 * 32]);
            }
            {
                const int r0 = wave * 16 + s * 8;
                const int row = r0 + wRow;
                const int cg = wPos ^ (row & 7);
                gl2lds16(W + (size_t)(nBase + row) * K + k0 + cg * 4, &Ws[r0 * 32]);
            }
        }
        __syncthreads();

        bf16x8 af[4], bfr[2];
#pragma unroll
        for (int i = 0; i < 4; i++) {
            const int rr = waveM * 64 + i * 16 + idx16;
            af[i] = *(const bf16x8*)&As16[rr * 32 + ((quad ^ (rr & 3)) * 8)];
        }
#pragma unroll
        for (int j = 0; j < 2; j++) {
            const int rr = waveN * 32 + j * 16 + idx16;
            const floatx4 b0 = *(const floatx4*)&Ws[rr * 32 + (((quad * 2) ^ (rr & 7)) * 4)];
            const floatx4 b1 = *(const floatx4*)&Ws[rr * 32 + (((quad * 2 + 1) ^ (rr & 7)) * 4)];
            bfr[j] = pack8(b0, b1);
        }
#pragma unroll
        for (int i = 0; i < 4; i++)
#pragma unroll
            for (int j = 0; j < 2; j++)
                acc[i][j] = MFMA16(af[i], bfr[j], acc[i][j]);
    }

#pragma unroll
    for (int i = 0; i < 4; i++) {
#pragma unroll
        for (int j = 0; j < 2; j++) {
            const int n = nBase + waveN * 32 + j * 16 + idx16;
#pragma unroll
            for (int r = 0; r < 4; r++) {
                const int m = mBase + waveM * 64 + i * 16 + quad * 4 + r;
                out[(size_t)m * Cc + n] = acc[i][j][r];
            }
        }
    }
}

extern "C" void kernel_launch(void* const* d_in, const int* in_sizes, int n_in,
                              void* d_out, int out_size, void* d_ws, size_t ws_size,
                              hipStream_t stream) {
    const float* x = nullptr;
    const float* w_qkv = nullptr;
    const float* w_proj = nullptr;
    for (int i = 0; i < n_in; i++) {
        if (in_sizes[i] == 4194304) x = (const float*)d_in[i];
        else if (in_sizes[i] == 3145728) w_qkv = (const float*)d_in[i];
        else if (in_sizes[i] == 1048576) w_proj = (const float*)d_in[i];
    }
    float* out = (float*)d_out;

    __hip_bfloat16* qkv = (__hip_bfloat16*)d_ws;        // q[4M] k[4M] v[4M]
    __hip_bfloat16* vbuf = qkv + 2 * QKV_STRIDE;        // v slot; becomes ao
    __hip_bfloat16* vt = qkv + 3 * QKV_STRIDE;          // 4M elems
    __hip_bfloat16* ao = vbuf;                          // attn out over dead v

    // bf16-input staging region after qkv+vt (8*QKV_STRIDE bytes = 32MB off)
    const size_t CVT_OFF = 8 * QKV_STRIDE;              // bytes
    const size_t NEED = CVT_OFF + (4194304 + 3145728) * sizeof(__hip_bfloat16);

    if (ws_size >= NEED) {
        __hip_bfloat16* xb = (__hip_bfloat16*)((char*)d_ws + CVT_OFF); // 8MB
        __hip_bfloat16* wbq = xb + 4194304;                            // 6MB
        __hip_bfloat16* wbp = qkv;    // q region, dead after attn_fa

        cvt_bf16<<<dim3(4194304 / 8 / 256), 256, 0, stream>>>(x, xb, 4194304 / 8);
        cvt_bf16<<<dim3(3145728 / 8 / 256), 256, 0, stream>>>(w_qkv, wbq, 3145728 / 8);
        gemm_qkv_bf16<<<dim3(4096 / 128, 3072 / 128), 256, 0, stream>>>(xb, wbq, qkv);
        transpose_v<<<dim3(Tc / 64, Hc, Bc), 256, 0, stream>>>(vbuf, vt);
        attn_fa<<<dim3(Tc / 128, Hc, Bc), 256, 0, stream>>>(qkv, vt, ao);
        cvt_bf16<<<dim3(1048576 / 8 / 256), 256, 0, stream>>>(w_proj, wbp, 1048576 / 8);
        gemm_proj_bf16<<<dim3(4096 / 128, 1024 / 64), 256, 0, stream>>>(ao, wbp, out);
    } else {
        gemm_qkv<<<dim3(4096 / 128, 3072 / 128), 256, 0, stream>>>(x, w_qkv, qkv);
        transpose_v<<<dim3(Tc / 64, Hc, Bc), 256, 0, stream>>>(vbuf, vt);
        attn_fa<<<dim3(Tc / 128, Hc, Bc), 256, 0, stream>>>(qkv, vt, ao);
        gemm_proj<<<dim3(4096 / 128, 1024 / 64), 256, 0, stream>>>(ao, w_proj, out);
    }
}

// Round 7
// 194.066 us; speedup vs baseline: 1.3804x; 1.0739x over previous
//
#include <hip/hip_runtime.h>
#include <hip/hip_bf16.h>

// ROUND 16: 8-wave paired-q-tile flash attention.
// R15 post-mortem: grid=512 (2 blocks/CU) with causal imbalance -> light
// blocks die early, tail runs 1 wave/SIMD; avg occupancy 11.8%, attn 77.6us.
// Fix: block = (pair p, h, b) with 8 waves: waves 0-3 own q-tile 15-p,
// waves 4-7 own q-tile p (tiles/block = 32-2p, spread 32:18 not 32:2);
// K/Vt staged once per block (1 gl2lds16 per thread per array) and shared by
// all 8 waves; wave-uniform skip guard (kt<=qtw) removes all-masked tiles.
// Per-tile compute identical to R15 (verified). LDS 68.6KB, grid 256 (1/CU),
// steady 2 waves/SIMD. GEMMs (bf16) / transpose / cvt unchanged.

typedef __attribute__((ext_vector_type(8))) short bf16x8;
typedef __attribute__((ext_vector_type(4))) short bf16x4;
typedef __attribute__((ext_vector_type(4))) float floatx4;

#define MFMA16(a, b, c) __builtin_amdgcn_mfma_f32_16x16x32_bf16((a), (b), (c), 0, 0, 0)

#if __has_builtin(__builtin_amdgcn_exp2f)
#define EXP2F(x) __builtin_amdgcn_exp2f(x)
#else
#define EXP2F(x) exp2f(x)
#endif

static constexpr int Bc = 2, Tc = 2048, Cc = 1024, Hc = 16, Dc = 64;
static constexpr size_t QKV_STRIDE = (size_t)Bc * Hc * Tc * Dc; // 4194304
static constexpr float KSL2E = 0.125f * 1.44269504088896f; // scale * log2(e)

__device__ __forceinline__ bf16x8 load8(const __hip_bfloat16* p) {
    return *(const bf16x8*)p;
}

__device__ __forceinline__ bf16x8 load8_lds(const __hip_bfloat16* p) {
    const bf16x4 lo = *(const bf16x4*)p;
    const bf16x4 hi = *(const bf16x4*)(p + 4);
    bf16x8 r;
    r[0] = lo[0]; r[1] = lo[1]; r[2] = lo[2]; r[3] = lo[3];
    r[4] = hi[0]; r[5] = hi[1]; r[6] = hi[2]; r[7] = hi[3];
    return r;
}

__device__ __forceinline__ short f2b(float x) {
    union { __hip_bfloat16 h; short s; } u;
    u.h = __float2bfloat16(x);
    return u.s;
}

__device__ __forceinline__ bf16x8 pack8(floatx4 a, floatx4 b) {
    bf16x8 r;
    r[0] = f2b(a[0]); r[1] = f2b(a[1]); r[2] = f2b(a[2]); r[3] = f2b(a[3]);
    r[4] = f2b(b[0]); r[5] = f2b(b[1]); r[6] = f2b(b[2]); r[7] = f2b(b[3]);
    return r;
}

__device__ __forceinline__ void gl2lds16(const void* g, void* l) {
    __builtin_amdgcn_global_load_lds(
        (const __attribute__((address_space(1))) void*)g,
        (__attribute__((address_space(3))) void*)l, 16, 0, 0);
}

// ================= f32 -> bf16 bulk convert (8 elems/thread) ================
__global__ __launch_bounds__(256) void cvt_bf16(
    const float* __restrict__ in, __hip_bfloat16* __restrict__ out, int n8) {
    const int i = blockIdx.x * 256 + threadIdx.x;
    if (i < n8) {
        const floatx4 a = *(const floatx4*)&in[(size_t)i * 8];
        const floatx4 b = *(const floatx4*)&in[(size_t)i * 8 + 4];
        *(bf16x8*)&out[(size_t)i * 8] = pack8(a, b);
    }
}

// ================= GEMM1 bf16 (R14): qkv = xb @ wb^T ========================
__global__ __launch_bounds__(256) void gemm_qkv_bf16(
    const __hip_bfloat16* __restrict__ A,
    const __hip_bfloat16* __restrict__ W,
    __hip_bfloat16* __restrict__ qkv) {
    __shared__ __hip_bfloat16 As16[128 * 32];
    __shared__ __hip_bfloat16 Bs16[128 * 32];
    const int K = Cc;
    const int lane = threadIdx.x & 63;
    const int wave = threadIdx.x >> 6;
    const int waveM = wave >> 1, waveN = wave & 1;
    const int mBase = blockIdx.x * 128;
    const int nBase = blockIdx.y * 128;
    const int idx16 = lane & 15;
    const int quad = lane >> 4;
    const int aRow = lane >> 2, aPos = lane & 3;

    floatx4 acc[4][4] = {};

    for (int k0 = 0; k0 < K; k0 += 32) {
        __syncthreads();
#pragma unroll
        for (int s = 0; s < 2; s++) {
            const int r0 = wave * 32 + s * 16;
            const int row = r0 + aRow;
            const int cg = aPos ^ (row & 3);
            gl2lds16(A + (size_t)(mBase + row) * K + k0 + cg * 8, &As16[r0 * 32]);
            gl2lds16(W + (size_t)(nBase + row) * K + k0 + cg * 8, &Bs16[r0 * 32]);
        }
        __syncthreads();

        bf16x8 af[4], bfr[4];
#pragma unroll
        for (int i = 0; i < 4; i++) {
            const int rr = waveM * 64 + i * 16 + idx16;
            af[i] = *(const bf16x8*)&As16[rr * 32 + ((quad ^ (rr & 3)) * 8)];
        }
#pragma unroll
        for (int j = 0; j < 4; j++) {
            const int rr = waveN * 64 + j * 16 + idx16;
            bfr[j] = *(const bf16x8*)&Bs16[rr * 32 + ((quad ^ (rr & 3)) * 8)];
        }
#pragma unroll
        for (int i = 0; i < 4; i++)
#pragma unroll
            for (int j = 0; j < 4; j++)
                acc[i][j] = MFMA16(af[i], bfr[j], acc[i][j]);
    }

#pragma unroll
    for (int i = 0; i < 4; i++) {
#pragma unroll
        for (int j = 0; j < 4; j++) {
            const int n = nBase + waveN * 64 + j * 16 + idx16;
            const int part = n >> 10;
            const int rem = n & 1023;
            const int h = rem >> 6, d = rem & 63;
#pragma unroll
            for (int r = 0; r < 4; r++) {
                const int m = mBase + waveM * 64 + i * 16 + quad * 4 + r;
                const int bb = m >> 11, t = m & 2047;
                const size_t o = (size_t)part * QKV_STRIDE +
                                 (((size_t)(bb * Hc + h)) * Tc + t) * Dc + d;
                qkv[o] = __float2bfloat16(acc[i][j][r]);
            }
        }
    }
}

// ================= GEMM2 bf16 (R14): out(f32) = ao @ wbp^T ==================
__global__ __launch_bounds__(256) void gemm_proj_bf16(
    const __hip_bfloat16* __restrict__ A,
    const __hip_bfloat16* __restrict__ W,
    float* __restrict__ out) {
    __shared__ __hip_bfloat16 As16[128 * 32];
    __shared__ __hip_bfloat16 Bs16[64 * 32];
    const int K = Cc;
    const int lane = threadIdx.x & 63;
    const int wave = threadIdx.x >> 6;
    const int waveM = wave >> 1, waveN = wave & 1;
    const int mBase = blockIdx.x * 128;
    const int nBase = blockIdx.y * 64;
    const int idx16 = lane & 15;
    const int quad = lane >> 4;
    const int aRow = lane >> 2, aPos = lane & 3;

    floatx4 acc[4][2] = {};

    for (int k0 = 0; k0 < K; k0 += 32) {
        __syncthreads();
#pragma unroll
        for (int s = 0; s < 2; s++) {
            const int r0 = wave * 32 + s * 16;
            const int row = r0 + aRow;
            const int cg = aPos ^ (row & 3);
            gl2lds16(A + (size_t)(mBase + row) * K + k0 + cg * 8, &As16[r0 * 32]);
        }
        {
            const int r0 = wave * 16;
            const int row = r0 + aRow;
            const int cg = aPos ^ (row & 3);
            gl2lds16(W + (size_t)(nBase + row) * K + k0 + cg * 8, &Bs16[r0 * 32]);
        }
        __syncthreads();

        bf16x8 af[4], bfr[2];
#pragma unroll
        for (int i = 0; i < 4; i++) {
            const int rr = waveM * 64 + i * 16 + idx16;
            af[i] = *(const bf16x8*)&As16[rr * 32 + ((quad ^ (rr & 3)) * 8)];
        }
#pragma unroll
        for (int j = 0; j < 2; j++) {
            const int rr = waveN * 32 + j * 16 + idx16;
            bfr[j] = *(const bf16x8*)&Bs16[rr * 32 + ((quad ^ (rr & 3)) * 8)];
        }
#pragma unroll
        for (int i = 0; i < 4; i++)
#pragma unroll
            for (int j = 0; j < 2; j++)
                acc[i][j] = MFMA16(af[i], bfr[j], acc[i][j]);
    }

#pragma unroll
    for (int i = 0; i < 4; i++) {
#pragma unroll
        for (int j = 0; j < 2; j++) {
            const int n = nBase + waveN * 32 + j * 16 + idx16;
#pragma unroll
            for (int r = 0; r < 4; r++) {
                const int m = mBase + waveM * 64 + i * 16 + quad * 4 + r;
                out[(size_t)m * Cc + n] = acc[i][j][r];
            }
        }
    }
}

// ================= V transpose (unchanged): [b,h,t,d] -> [b,h,d,t] ==========
__global__ __launch_bounds__(256) void transpose_v(
    const __hip_bfloat16* __restrict__ v,
    __hip_bfloat16* __restrict__ vt) {
    __shared__ unsigned short tile[64][65];
    const int t0 = blockIdx.x * 64;
    const int h = blockIdx.y, b = blockIdx.z;
    const size_t base = ((size_t)(b * Hc + h)) * Tc * Dc;
    const unsigned short* vp = (const unsigned short*)v + base;
    unsigned short* vtp = (unsigned short*)vt + base;

    for (int e = threadIdx.x; e < 4096; e += 256) {
        const int tl = e >> 6, d = e & 63;
        tile[tl][d] = vp[(size_t)(t0 + tl) * Dc + d];
    }
    __syncthreads();
    for (int e = threadIdx.x; e < 4096; e += 256) {
        const int d = e >> 6, tl = e & 63;
        vtp[(size_t)d * Tc + t0 + tl] = tile[tl][d];
    }
}

// ================= Flash attention v8: 8-wave paired q-tiles ================
// Block = (pair p, h, b), 512 threads. Waves 0-3: q-tile 15-p (rows
// (15-p)*128 + w*32); waves 4-7: q-tile p (rows p*128 + (w-4)*32).
// K/Vt (64x64 bf16) staged via global_load_lds (1 issue per thread per
// array), double-buffered, shared by all 8 waves. Swizzle per rule #21:
// linear LDS dest + inverse-swizzled global src (chunk^=row&7) + swizzled
// read. nt = 32-2p tiles; wave-uniform guard kt<=qtw skips all-masked tiles.
__global__ __launch_bounds__(512) void attn_fa8(
    const __hip_bfloat16* __restrict__ qkv,
    const __hip_bfloat16* __restrict__ vt,
    __hip_bfloat16* __restrict__ aout) {
    __shared__ __hip_bfloat16 kbuf[2][64 * 64];   // 8KB each
    __shared__ __hip_bfloat16 vbuf2[2][64 * 64];  // 8KB each
    __shared__ __hip_bfloat16 lds_p[8][2][16][72];

    const int lane = threadIdx.x & 63;
    const int wave = threadIdx.x >> 6;            // 0..7
    const int col = lane & 15;
    const int quad = lane >> 4;
    const int p = blockIdx.x;                     // pair index 0..7
    const int h = blockIdx.y;
    const int b = blockIdx.z;

    const int qt = (wave < 4) ? (15 - p) : p;     // per-wave q-tile
    const int qBase = qt * 128 + (wave & 3) * 32; // this wave's 32 q-rows
    const int nt = 2 * (15 - p) + 2;              // block tile count (32-2p)
    const int qtw = (qBase + 31) >> 6;            // last tile this wave needs

    const size_t headOff = ((size_t)(b * Hc + h)) * Tc * Dc;
    const __hip_bfloat16* qp = qkv + headOff;
    const __hip_bfloat16* kp = qkv + QKV_STRIDE + headOff;
    const __hip_bfloat16* vtp = vt + headOff;     // [d][t] within head

    const int qrowA = qBase + col;                // frag A rows
    const int qrowB = qrowA + 16;                 // frag B rows
    bf16x8 qfa[2], qfb[2];
    qfa[0] = load8(qp + (size_t)qrowA * Dc + quad * 8);
    qfa[1] = load8(qp + (size_t)qrowA * Dc + 32 + quad * 8);
    qfb[0] = load8(qp + (size_t)qrowB * Dc + quad * 8);
    qfb[1] = load8(qp + (size_t)qrowB * Dc + 32 + quad * 8);

    floatx4 oa[4] = {}, ob[4] = {};
    float la[4] = {0.f, 0.f, 0.f, 0.f}, lb[4] = {0.f, 0.f, 0.f, 0.f};
    const int q0a = qBase + quad * 4;
    const int q0b = q0a + 16;

    // stage tile kt: 8 waves x 8 rows each; LDS dest linear (wave-uniform
    // base + lane*16), global source chunk inverse-swizzled g=(lane&7)^(row&7)
    auto stage = [&](int kt, int buf) {
        const int keyBase = kt * 64;
        const int row = wave * 8 + (lane >> 3);   // 0..63
        const int g = (lane & 7) ^ (row & 7);
        gl2lds16(kp + (size_t)(keyBase + row) * Dc + g * 8,
                 &kbuf[buf][wave * 512]);
        gl2lds16(vtp + (size_t)row * Tc + keyBase + g * 8,
                 &vbuf2[buf][wave * 512]);
    };

    stage(0, 0);
    int cur = 0;

    for (int kt = 0; kt < nt; kt++) {
        const int keyBase = kt * 64;
        __syncthreads();                    // buf[cur] staged (vmcnt drained)
        if (kt + 1 < nt) stage(kt + 1, cur ^ 1);   // prefetch overlaps compute

        if (kt <= qtw) {
            // --- read K/Vt frags from swizzled LDS ---
            bf16x8 kc0[4], kc1[4], vc0[4], vc1[4];
#pragma unroll
            for (int j = 0; j < 4; j++) {
                const int kr = j * 16 + col;        // local key row / d row
                const int m = kr & 7;
                kc0[j] = load8(&kbuf[cur][kr * 64 + ((quad * 8) ^ (m * 8))]);
                kc1[j] = load8(&kbuf[cur][kr * 64 + ((32 + quad * 8) ^ (m * 8))]);
                vc0[j] = load8(&vbuf2[cur][kr * 64 + ((quad * 8) ^ (m * 8))]);
                vc1[j] = load8(&vbuf2[cur][kr * 64 + ((32 + quad * 8) ^ (m * 8))]);
            }

            // --- S = Q K^T for both q-frags ---
            floatx4 sa[4], sb[4];
#pragma unroll
            for (int j = 0; j < 4; j++) {
                floatx4 a0 = {0.f, 0.f, 0.f, 0.f};
                a0 = MFMA16(qfa[0], kc0[j], a0);
                sa[j] = MFMA16(qfa[1], kc1[j], a0);
                floatx4 b0 = {0.f, 0.f, 0.f, 0.f};
                b0 = MFMA16(qfb[0], kc0[j], b0);
                sb[j] = MFMA16(qfb[1], kc1[j], b0);
            }

            // --- P = exp2(s*KSL2E), branchless causal mask, per-lane l ---
#pragma unroll
            for (int j = 0; j < 4; j++) {
                const int key = keyBase + j * 16 + col;
#pragma unroll
                for (int r = 0; r < 4; r++) {
                    float pa = EXP2F(sa[j][r] * KSL2E);
                    pa = (key > q0a + r) ? 0.f : pa;
                    la[r] += pa;
                    lds_p[wave][0][quad * 4 + r][j * 16 + col] = __float2bfloat16(pa);
                    float pb = EXP2F(sb[j][r] * KSL2E);
                    pb = (key > q0b + r) ? 0.f : pb;
                    lb[r] += pb;
                    lds_p[wave][1][quad * 4 + r][j * 16 + col] = __float2bfloat16(pb);
                }
            }

            // --- O += P V ---
            const bf16x8 pa0 = load8_lds(&lds_p[wave][0][col][quad * 8]);
            const bf16x8 pa1 = load8_lds(&lds_p[wave][0][col][32 + quad * 8]);
            const bf16x8 pb0 = load8_lds(&lds_p[wave][1][col][quad * 8]);
            const bf16x8 pb1 = load8_lds(&lds_p[wave][1][col][32 + quad * 8]);
#pragma unroll
            for (int j = 0; j < 4; j++) {
                oa[j] = MFMA16(pa0, vc0[j], oa[j]);
                oa[j] = MFMA16(pa1, vc1[j], oa[j]);
                ob[j] = MFMA16(pb0, vc0[j], ob[j]);
                ob[j] = MFMA16(pb1, vc1[j], ob[j]);
            }
        }

        __syncthreads();                    // all waves done with buf[cur]
        cur ^= 1;
    }

    // --- reduce l across the 16 col-lanes of each quad group ---
#pragma unroll
    for (int off = 1; off < 16; off <<= 1)
#pragma unroll
        for (int r = 0; r < 4; r++) {
            la[r] += __shfl_xor(la[r], off, 64);
            lb[r] += __shfl_xor(lb[r], off, 64);
        }

#pragma unroll
    for (int j = 0; j < 4; j++) {
        const int d = j * 16 + col;
#pragma unroll
        for (int r = 0; r < 4; r++) {
            const int ta = q0a + r;
            aout[((size_t)(b * Tc + ta)) * Cc + h * 64 + d] =
                __float2bfloat16(oa[j][r] / la[r]);
            const int tb = q0b + r;
            aout[((size_t)(b * Tc + tb)) * Cc + h * 64 + d] =
                __float2bfloat16(ob[j][r] / lb[r]);
        }
    }
}

// ======== Fallback f32-staging GEMMs (used only if ws too small) ============
__global__ __launch_bounds__(256) void gemm_qkv(
    const float* __restrict__ A,
    const float* __restrict__ W,
    __hip_bfloat16* __restrict__ qkv) {
    __shared__ float As[128 * 32];
    __shared__ float Bs[128 * 32];
    const int K = Cc;
    const int lane = threadIdx.x & 63;
    const int wave = threadIdx.x >> 6;
    const int waveM = wave >> 1, waveN = wave & 1;
    const int mBase = blockIdx.x * 128;
    const int nBase = blockIdx.y * 128;
    const int idx16 = lane & 15;
    const int quad = lane >> 4;
    const int ldRow = lane >> 3;
    const int ldPos = lane & 7;

    floatx4 acc[4][4] = {};

    for (int k0 = 0; k0 < K; k0 += 32) {
        __syncthreads();
#pragma unroll
        for (int s = 0; s < 4; s++) {
            const int r0 = wave * 32 + s * 8;
            const int row = r0 + ldRow;
            const int cg = ldPos ^ (row & 7);
            gl2lds16(A + (size_t)(mBase + row) * K + k0 + cg * 4, &As[r0 * 32]);
            gl2lds16(W + (size_t)(nBase + row) * K + k0 + cg * 4, &Bs[r0 * 32]);
        }
        __syncthreads();

        bf16x8 af[4], bfr[4];
#pragma unroll
        for (int i = 0; i < 4; i++) {
            const int rr = waveM * 64 + i * 16 + idx16;
            const floatx4 a0 = *(const floatx4*)&As[rr * 32 + (((quad * 2) ^ (rr & 7)) * 4)];
            const floatx4 a1 = *(const floatx4*)&As[rr * 32 + (((quad * 2 + 1) ^ (rr & 7)) * 4)];
            af[i] = pack8(a0, a1);
        }
#pragma unroll
        for (int j = 0; j < 4; j++) {
            const int rr = waveN * 64 + j * 16 + idx16;
            const floatx4 b0 = *(const floatx4*)&Bs[rr * 32 + (((quad * 2) ^ (rr & 7)) * 4)];
            const floatx4 b1 = *(const floatx4*)&Bs[rr * 32 + (((quad * 2 + 1) ^ (rr & 7)) * 4)];
            bfr[j] = pack8(b0, b1);
        }
#pragma unroll
        for (int i = 0; i < 4; i++)
#pragma unroll
            for (int j = 0; j < 4; j++)
                acc[i][j] = MFMA16(af[i], bfr[j], acc[i][j]);
    }

#pragma unroll
    for (int i = 0; i < 4; i++) {
#pragma unroll
        for (int j = 0; j < 4; j++) {
            const int n = nBase + waveN * 64 + j * 16 + idx16;
            const int part = n >> 10;
            const int rem = n & 1023;
            const int h = rem >> 6, d = rem & 63;
#pragma unroll
            for (int r = 0; r < 4; r++) {
                const int m = mBase + waveM * 64 + i * 16 + quad * 4 + r;
                const int bb = m >> 11, t = m & 2047;
                const size_t o = (size_t)part * QKV_STRIDE +
                                 (((size_t)(bb * Hc + h)) * Tc + t) * Dc + d;
                qkv[o] = __float2bfloat16(acc[i][j][r]);
            }
        }
    }
}

__global__ __launch_bounds__(256) void gemm_proj(
    const __hip_bfloat16* __restrict__ A,
    const float* __restrict__ W,
    float* __restrict__ out) {
    __shared__ __hip_bfloat16 As16[128 * 32];
    __shared__ float Ws[64 * 32];
    const int K = Cc;
    const int lane = threadIdx.x & 63;
    const int wave = threadIdx.x >> 6;
    const int waveM = wave >> 1, waveN = wave & 1;
    const int mBase = blockIdx.x * 128;
    const int nBase = blockIdx.y * 64;
    const int idx16 = lane & 15;
    const int quad = lane >> 4;
    const int aRow = lane >> 2, aPos = lane & 3;
    const int wRow = lane >> 3, wPos = lane & 7;

    floatx4 acc[4][2] = {};

    for (int k0 = 0; k0 < K; k0 += 32) {
        __syncthreads();
#pragma unroll
        for (int s = 0; s < 2; s++) {
            {
                const int r0 = wave * 32 + s * 16;
                const int row = r0 + aRow;
                const int cg = aPos ^ (row & 3);
                gl2lds16(A + (size_t)(mBase + row) * K + k0 + cg * 8, &As16[r0 * 32]);
            }
            {
                const int r0 = wave * 16 + s * 8;
                const int row = r0 + wRow;
                const int cg = wPos ^ (row & 7);
                gl2lds16(W + (size_t)(nBase + row) * K + k0 + cg * 4, &Ws[r0 * 32]);
            }
        }
        __syncthreads();

        bf16x8 af[4], bfr[2];
#pragma unroll
        for (int i = 0; i < 4; i++) {
            const int rr = waveM * 64 + i * 16 + idx16;
            af[i] = *(const bf16x8*)&As16[rr * 32 + ((quad ^ (rr & 3)) * 8)];
        }
#pragma unroll
        for (int j = 0; j < 2; j++) {
            const int rr = waveN * 32 + j * 16 + idx16;
            const floatx4 b0 = *(const floatx4*)&Ws[rr * 32 + (((quad * 2) ^ (rr & 7)) * 4)];
            const floatx4 b1 = *(const floatx4*)&Ws[rr * 32 + (((quad * 2 + 1) ^ (rr & 7)) * 4)];
            bfr[j] = pack8(b0, b1);
        }
#pragma unroll
        for (int i = 0; i < 4; i++)
#pragma unroll
            for (int j = 0; j < 2; j++)
                acc[i][j] = MFMA16(af[i], bfr[j], acc[i][j]);
    }

#pragma unroll
    for (int i = 0; i < 4; i++) {
#pragma unroll
        for (int j = 0; j < 2; j++) {
            const int n = nBase + waveN * 32 + j * 16 + idx16;
#pragma unroll
            for (int r = 0; r < 4; r++) {
                const int m = mBase + waveM * 64 + i * 16 + quad * 4 + r;
                out[(size_t)m * Cc + n] = acc[i][j][r];
            }
        }
    }
}

extern "C" void kernel_launch(void* const* d_in, const int* in_sizes, int n_in,
                              void* d_out, int out_size, void* d_ws, size_t ws_size,
                              hipStream_t stream) {
    const float* x = nullptr;
    const float* w_qkv = nullptr;
    const float* w_proj = nullptr;
    for (int i = 0; i < n_in; i++) {
        if (in_sizes[i] == 4194304) x = (const float*)d_in[i];
        else if (in_sizes[i] == 3145728) w_qkv = (const float*)d_in[i];
        else if (in_sizes[i] == 1048576) w_proj = (const float*)d_in[i];
    }
    float* out = (float*)d_out;

    __hip_bfloat16* qkv = (__hip_bfloat16*)d_ws;        // q[4M] k[4M] v[4M]
    __hip_bfloat16* vbuf = qkv + 2 * QKV_STRIDE;        // v slot; becomes ao
    __hip_bfloat16* vt = qkv + 3 * QKV_STRIDE;          // 4M elems
    __hip_bfloat16* ao = vbuf;                          // attn out over dead v

    // bf16-input staging region after qkv+vt (8*QKV_STRIDE bytes = 32MB off)
    const size_t CVT_OFF = 8 * QKV_STRIDE;              // bytes
    const size_t NEED = CVT_OFF + (4194304 + 3145728) * sizeof(__hip_bfloat16);

    if (ws_size >= NEED) {
        __hip_bfloat16* xb = (__hip_bfloat16*)((char*)d_ws + CVT_OFF); // 8MB
        __hip_bfloat16* wbq = xb + 4194304;                            // 6MB
        __hip_bfloat16* wbp = qkv;    // q region, dead after attn

        cvt_bf16<<<dim3(4194304 / 8 / 256), 256, 0, stream>>>(x, xb, 4194304 / 8);
        cvt_bf16<<<dim3(3145728 / 8 / 256), 256, 0, stream>>>(w_qkv, wbq, 3145728 / 8);
        gemm_qkv_bf16<<<dim3(4096 / 128, 3072 / 128), 256, 0, stream>>>(xb, wbq, qkv);
        transpose_v<<<dim3(Tc / 64, Hc, Bc), 256, 0, stream>>>(vbuf, vt);
        attn_fa8<<<dim3(8, Hc, Bc), 512, 0, stream>>>(qkv, vt, ao);
        cvt_bf16<<<dim3(1048576 / 8 / 256), 256, 0, stream>>>(w_proj, wbp, 1048576 / 8);
        gemm_proj_bf16<<<dim3(4096 / 128, 1024 / 64), 256, 0, stream>>>(ao, wbp, out);
    } else {
        gemm_qkv<<<dim3(4096 / 128, 3072 / 128), 256, 0, stream>>>(x, w_qkv, qkv);
        transpose_v<<<dim3(Tc / 64, Hc, Bc), 256, 0, stream>>>(vbuf, vt);
        attn_fa8<<<dim3(8, Hc, Bc), 512, 0, stream>>>(qkv, vt, ao);
        gemm_proj<<<dim3(4096 / 128, 1024 / 64), 256, 0, stream>>>(ao, w_proj, out);
    }
}

// Round 8
// 183.661 us; speedup vs baseline: 1.4586x; 1.0567x over previous
//
#include <hip/hip_runtime.h>
#include <hip/hip_bf16.h>

// ROUND 17: folded split-K flash attention — uniform 17-step blocks.
// R16 post-mortem: per-CU work uniform but light waves idle after 2p+2 of
// 32-2p steps -> CU decays to 1 wave/SIMD. Fix (m=0 partials sum linearly):
// waves 0-3 = heavy rows, key tiles [0,17); waves 4-7 = light tile fully
// (tiles [0,2p+2), output stored mid-loop), then heavy-row partials over
// tiles [17,32-2p). Every wave: exactly 17 steps. Stream A staged as before
// (shared by B's light phase - same key tiles); stream B has own buffers for
// kt>=17. End: B waves' heavy partials added to A waves' via LDS (staging
// region dead), no atomics. Per-tile compute identical to R16.
// LDS 100KB (1 block/CU, 8 waves steady). GEMMs/transpose/cvt unchanged.

typedef __attribute__((ext_vector_type(8))) short bf16x8;
typedef __attribute__((ext_vector_type(4))) short bf16x4;
typedef __attribute__((ext_vector_type(4))) float floatx4;

#define MFMA16(a, b, c) __builtin_amdgcn_mfma_f32_16x16x32_bf16((a), (b), (c), 0, 0, 0)

#if __has_builtin(__builtin_amdgcn_exp2f)
#define EXP2F(x) __builtin_amdgcn_exp2f(x)
#else
#define EXP2F(x) exp2f(x)
#endif

static constexpr int Bc = 2, Tc = 2048, Cc = 1024, Hc = 16, Dc = 64;
static constexpr size_t QKV_STRIDE = (size_t)Bc * Hc * Tc * Dc; // 4194304
static constexpr float KSL2E = 0.125f * 1.44269504088896f; // scale * log2(e)

__device__ __forceinline__ bf16x8 load8(const __hip_bfloat16* p) {
    return *(const bf16x8*)p;
}

__device__ __forceinline__ bf16x8 load8_lds(const __hip_bfloat16* p) {
    const bf16x4 lo = *(const bf16x4*)p;
    const bf16x4 hi = *(const bf16x4*)(p + 4);
    bf16x8 r;
    r[0] = lo[0]; r[1] = lo[1]; r[2] = lo[2]; r[3] = lo[3];
    r[4] = hi[0]; r[5] = hi[1]; r[6] = hi[2]; r[7] = hi[3];
    return r;
}

__device__ __forceinline__ short f2b(float x) {
    union { __hip_bfloat16 h; short s; } u;
    u.h = __float2bfloat16(x);
    return u.s;
}

__device__ __forceinline__ bf16x8 pack8(floatx4 a, floatx4 b) {
    bf16x8 r;
    r[0] = f2b(a[0]); r[1] = f2b(a[1]); r[2] = f2b(a[2]); r[3] = f2b(a[3]);
    r[4] = f2b(b[0]); r[5] = f2b(b[1]); r[6] = f2b(b[2]); r[7] = f2b(b[3]);
    return r;
}

__device__ __forceinline__ void gl2lds16(const void* g, void* l) {
    __builtin_amdgcn_global_load_lds(
        (const __attribute__((address_space(1))) void*)g,
        (__attribute__((address_space(3))) void*)l, 16, 0, 0);
}

// ================= f32 -> bf16 bulk convert (8 elems/thread) ================
__global__ __launch_bounds__(256) void cvt_bf16(
    const float* __restrict__ in, __hip_bfloat16* __restrict__ out, int n8) {
    const int i = blockIdx.x * 256 + threadIdx.x;
    if (i < n8) {
        const floatx4 a = *(const floatx4*)&in[(size_t)i * 8];
        const floatx4 b = *(const floatx4*)&in[(size_t)i * 8 + 4];
        *(bf16x8*)&out[(size_t)i * 8] = pack8(a, b);
    }
}

// ================= GEMM1 bf16 (R14): qkv = xb @ wb^T ========================
__global__ __launch_bounds__(256) void gemm_qkv_bf16(
    const __hip_bfloat16* __restrict__ A,
    const __hip_bfloat16* __restrict__ W,
    __hip_bfloat16* __restrict__ qkv) {
    __shared__ __hip_bfloat16 As16[128 * 32];
    __shared__ __hip_bfloat16 Bs16[128 * 32];
    const int K = Cc;
    const int lane = threadIdx.x & 63;
    const int wave = threadIdx.x >> 6;
    const int waveM = wave >> 1, waveN = wave & 1;
    const int mBase = blockIdx.x * 128;
    const int nBase = blockIdx.y * 128;
    const int idx16 = lane & 15;
    const int quad = lane >> 4;
    const int aRow = lane >> 2, aPos = lane & 3;

    floatx4 acc[4][4] = {};

    for (int k0 = 0; k0 < K; k0 += 32) {
        __syncthreads();
#pragma unroll
        for (int s = 0; s < 2; s++) {
            const int r0 = wave * 32 + s * 16;
            const int row = r0 + aRow;
            const int cg = aPos ^ (row & 3);
            gl2lds16(A + (size_t)(mBase + row) * K + k0 + cg * 8, &As16[r0 * 32]);
            gl2lds16(W + (size_t)(nBase + row) * K + k0 + cg * 8, &Bs16[r0 * 32]);
        }
        __syncthreads();

        bf16x8 af[4], bfr[4];
#pragma unroll
        for (int i = 0; i < 4; i++) {
            const int rr = waveM * 64 + i * 16 + idx16;
            af[i] = *(const bf16x8*)&As16[rr * 32 + ((quad ^ (rr & 3)) * 8)];
        }
#pragma unroll
        for (int j = 0; j < 4; j++) {
            const int rr = waveN * 64 + j * 16 + idx16;
            bfr[j] = *(const bf16x8*)&Bs16[rr * 32 + ((quad ^ (rr & 3)) * 8)];
        }
#pragma unroll
        for (int i = 0; i < 4; i++)
#pragma unroll
            for (int j = 0; j < 4; j++)
                acc[i][j] = MFMA16(af[i], bfr[j], acc[i][j]);
    }

#pragma unroll
    for (int i = 0; i < 4; i++) {
#pragma unroll
        for (int j = 0; j < 4; j++) {
            const int n = nBase + waveN * 64 + j * 16 + idx16;
            const int part = n >> 10;
            const int rem = n & 1023;
            const int h = rem >> 6, d = rem & 63;
#pragma unroll
            for (int r = 0; r < 4; r++) {
                const int m = mBase + waveM * 64 + i * 16 + quad * 4 + r;
                const int bb = m >> 11, t = m & 2047;
                const size_t o = (size_t)part * QKV_STRIDE +
                                 (((size_t)(bb * Hc + h)) * Tc + t) * Dc + d;
                qkv[o] = __float2bfloat16(acc[i][j][r]);
            }
        }
    }
}

// ================= GEMM2 bf16 (R14): out(f32) = ao @ wbp^T ==================
__global__ __launch_bounds__(256) void gemm_proj_bf16(
    const __hip_bfloat16* __restrict__ A,
    const __hip_bfloat16* __restrict__ W,
    float* __restrict__ out) {
    __shared__ __hip_bfloat16 As16[128 * 32];
    __shared__ __hip_bfloat16 Bs16[64 * 32];
    const int K = Cc;
    const int lane = threadIdx.x & 63;
    const int wave = threadIdx.x >> 6;
    const int waveM = wave >> 1, waveN = wave & 1;
    const int mBase = blockIdx.x * 128;
    const int nBase = blockIdx.y * 64;
    const int idx16 = lane & 15;
    const int quad = lane >> 4;
    const int aRow = lane >> 2, aPos = lane & 3;

    floatx4 acc[4][2] = {};

    for (int k0 = 0; k0 < K; k0 += 32) {
        __syncthreads();
#pragma unroll
        for (int s = 0; s < 2; s++) {
            const int r0 = wave * 32 + s * 16;
            const int row = r0 + aRow;
            const int cg = aPos ^ (row & 3);
            gl2lds16(A + (size_t)(mBase + row) * K + k0 + cg * 8, &As16[r0 * 32]);
        }
        {
            const int r0 = wave * 16;
            const int row = r0 + aRow;
            const int cg = aPos ^ (row & 3);
            gl2lds16(W + (size_t)(nBase + row) * K + k0 + cg * 8, &Bs16[r0 * 32]);
        }
        __syncthreads();

        bf16x8 af[4], bfr[2];
#pragma unroll
        for (int i = 0; i < 4; i++) {
            const int rr = waveM * 64 + i * 16 + idx16;
            af[i] = *(const bf16x8*)&As16[rr * 32 + ((quad ^ (rr & 3)) * 8)];
        }
#pragma unroll
        for (int j = 0; j < 2; j++) {
            const int rr = waveN * 32 + j * 16 + idx16;
            bfr[j] = *(const bf16x8*)&Bs16[rr * 32 + ((quad ^ (rr & 3)) * 8)];
        }
#pragma unroll
        for (int i = 0; i < 4; i++)
#pragma unroll
            for (int j = 0; j < 2; j++)
                acc[i][j] = MFMA16(af[i], bfr[j], acc[i][j]);
    }

#pragma unroll
    for (int i = 0; i < 4; i++) {
#pragma unroll
        for (int j = 0; j < 2; j++) {
            const int n = nBase + waveN * 32 + j * 16 + idx16;
#pragma unroll
            for (int r = 0; r < 4; r++) {
                const int m = mBase + waveM * 64 + i * 16 + quad * 4 + r;
                out[(size_t)m * Cc + n] = acc[i][j][r];
            }
        }
    }
}

// ================= V transpose (unchanged): [b,h,t,d] -> [b,h,d,t] ==========
__global__ __launch_bounds__(256) void transpose_v(
    const __hip_bfloat16* __restrict__ v,
    __hip_bfloat16* __restrict__ vt) {
    __shared__ unsigned short tile[64][65];
    const int t0 = blockIdx.x * 64;
    const int h = blockIdx.y, b = blockIdx.z;
    const size_t base = ((size_t)(b * Hc + h)) * Tc * Dc;
    const unsigned short* vp = (const unsigned short*)v + base;
    unsigned short* vtp = (unsigned short*)vt + base;

    for (int e = threadIdx.x; e < 4096; e += 256) {
        const int tl = e >> 6, d = e & 63;
        tile[tl][d] = vp[(size_t)(t0 + tl) * Dc + d];
    }
    __syncthreads();
    for (int e = threadIdx.x; e < 4096; e += 256) {
        const int d = e >> 6, tl = e & 63;
        vtp[(size_t)d * Tc + t0 + tl] = tile[tl][d];
    }
}

// ================= Flash attention v9: folded split-K, 17 uniform steps =====
// Block = (p, h, b), 512 threads, p in 0..7. H = 15-p (heavy tile), L = p.
// Waves 0-3: heavy rows H*128 + w*32, key tiles [0,17) from stream A.
// Waves 4-7: light rows L*128 + w'*32 over tiles [0,2p+2) (reads stream A,
// same key tiles; output stored at transition), then heavy rows (same rows
// as wave w') over tiles [17,32-2p) from stream B. All waves: 17 steps.
// End: B heavy partials (O,l) added to A's via LDS combine (m=0 softmax).
__global__ __launch_bounds__(512) void attn_fold(
    const __hip_bfloat16* __restrict__ qkv,
    const __hip_bfloat16* __restrict__ vt,
    __hip_bfloat16* __restrict__ aout) {
    // 100KB carved LDS: A-K, A-V, B-K, B-V (each dbuf 2x8KB), P (36KB).
    __shared__ floatx4 smem4[6400];
    char* const smem = (char*)smem4;
    __hip_bfloat16* const kA = (__hip_bfloat16*)smem;        // [2][4096]
    __hip_bfloat16* const vA = kA + 8192;                    // [2][4096]
    __hip_bfloat16* const kB = vA + 8192;                    // [2][4096]
    __hip_bfloat16* const vB = kB + 8192;                    // [2][4096]
    __hip_bfloat16* const Pb = vB + 8192;                    // [8][2][16][72]
    float* const comb = (float*)smem;                        // 40KB, post-loop

    const int lane = threadIdx.x & 63;
    const int wave = threadIdx.x >> 6;            // 0..7
    const int col = lane & 15;
    const int quad = lane >> 4;
    const int p = blockIdx.x;                     // 0..7
    const int h = blockIdx.y;
    const int b = blockIdx.z;
    const int H = 15 - p, L = p;
    const int lightEnd = 2 * p + 2;               // light phase length
    const int w3 = wave & 3;

    const size_t headOff = ((size_t)(b * Hc + h)) * Tc * Dc;
    const __hip_bfloat16* qp = qkv + headOff;
    const __hip_bfloat16* kp = qkv + QKV_STRIDE + headOff;
    const __hip_bfloat16* vtp = vt + headOff;     // [d][t] within head

    // --- current q-block state (B waves switch at transition) ---
    int qB = ((wave < 4) ? H : L) * 128 + w3 * 32;
    int qtw = (qB + 31) >> 6;
    int q0a = qB + quad * 4;
    int q0b = q0a + 16;
    bf16x8 qfa[2], qfb[2];
    {
        const int qrA = qB + col, qrB = qrA + 16;
        qfa[0] = load8(qp + (size_t)qrA * Dc + quad * 8);
        qfa[1] = load8(qp + (size_t)qrA * Dc + 32 + quad * 8);
        qfb[0] = load8(qp + (size_t)qrB * Dc + quad * 8);
        qfb[1] = load8(qp + (size_t)qrB * Dc + 32 + quad * 8);
    }

    floatx4 oa[4] = {}, ob[4] = {};
    float la[4] = {0.f, 0.f, 0.f, 0.f}, lb[4] = {0.f, 0.f, 0.f, 0.f};

    // stage key tile kt into a stream's buf half (4 waves, 64 rows K + V)
    auto stageA = [&](int kt, int buf) {
        const int keyBase = kt * 64;
#pragma unroll
        for (int s = 0; s < 2; s++) {
            const int blk = w3 * 2 + s;               // 0..7
            const int row = blk * 8 + (lane >> 3);    // 0..63
            const int g = (lane & 7) ^ (row & 7);
            gl2lds16(kp + (size_t)(keyBase + row) * Dc + g * 8,
                     kA + buf * 4096 + blk * 512);
            gl2lds16(vtp + (size_t)row * Tc + keyBase + g * 8,
                     vA + buf * 4096 + blk * 512);
        }
    };
    auto stageB = [&](int kt, int buf) {
        const int keyBase = kt * 64;
#pragma unroll
        for (int s = 0; s < 2; s++) {
            const int blk = w3 * 2 + s;
            const int row = blk * 8 + (lane >> 3);
            const int g = (lane & 7) ^ (row & 7);
            gl2lds16(kp + (size_t)(keyBase + row) * Dc + g * 8,
                     kB + buf * 4096 + blk * 512);
            gl2lds16(vtp + (size_t)row * Tc + keyBase + g * 8,
                     vB + buf * 4096 + blk * 512);
        }
    };

    // per-tile compute: frags from swizzled LDS, QK^T -> exp2+mask -> PV
    auto computeTile = [&](const __hip_bfloat16* kS, const __hip_bfloat16* vS,
                           int keyBase) {
        bf16x8 kc0[4], kc1[4], vc0[4], vc1[4];
#pragma unroll
        for (int j = 0; j < 4; j++) {
            const int kr = j * 16 + col;
            const int m8 = (kr & 7) * 8;
            kc0[j] = load8(&kS[kr * 64 + ((quad * 8) ^ m8)]);
            kc1[j] = load8(&kS[kr * 64 + ((32 + quad * 8) ^ m8)]);
            vc0[j] = load8(&vS[kr * 64 + ((quad * 8) ^ m8)]);
            vc1[j] = load8(&vS[kr * 64 + ((32 + quad * 8) ^ m8)]);
        }

        floatx4 sa[4], sb[4];
#pragma unroll
        for (int j = 0; j < 4; j++) {
            floatx4 a0 = {0.f, 0.f, 0.f, 0.f};
            a0 = MFMA16(qfa[0], kc0[j], a0);
            sa[j] = MFMA16(qfa[1], kc1[j], a0);
            floatx4 b0 = {0.f, 0.f, 0.f, 0.f};
            b0 = MFMA16(qfb[0], kc0[j], b0);
            sb[j] = MFMA16(qfb[1], kc1[j], b0);
        }

        __hip_bfloat16* Pw = Pb + (size_t)wave * 2304;   // [2][16][72]
#pragma unroll
        for (int j = 0; j < 4; j++) {
            const int key = keyBase + j * 16 + col;
#pragma unroll
            for (int r = 0; r < 4; r++) {
                float pa = EXP2F(sa[j][r] * KSL2E);
                pa = (key > q0a + r) ? 0.f : pa;
                la[r] += pa;
                Pw[(quad * 4 + r) * 72 + j * 16 + col] = __float2bfloat16(pa);
                float pb = EXP2F(sb[j][r] * KSL2E);
                pb = (key > q0b + r) ? 0.f : pb;
                lb[r] += pb;
                Pw[1152 + (quad * 4 + r) * 72 + j * 16 + col] = __float2bfloat16(pb);
            }
        }

        const bf16x8 pa0 = load8_lds(&Pw[col * 72 + quad * 8]);
        const bf16x8 pa1 = load8_lds(&Pw[col * 72 + 32 + quad * 8]);
        const bf16x8 pb0 = load8_lds(&Pw[1152 + col * 72 + quad * 8]);
        const bf16x8 pb1 = load8_lds(&Pw[1152 + col * 72 + 32 + quad * 8]);
#pragma unroll
        for (int j = 0; j < 4; j++) {
            oa[j] = MFMA16(pa0, vc0[j], oa[j]);
            oa[j] = MFMA16(pa1, vc1[j], oa[j]);
            ob[j] = MFMA16(pb0, vc0[j], ob[j]);
            ob[j] = MFMA16(pb1, vc1[j], ob[j]);
        }
    };

    // l-reduce + store output for current (oa,ob,la,lb) at q-base qB_
    auto outStore = [&](int qB_) {
#pragma unroll
        for (int off = 1; off < 16; off <<= 1)
#pragma unroll
            for (int r = 0; r < 4; r++) {
                la[r] += __shfl_xor(la[r], off, 64);
                lb[r] += __shfl_xor(lb[r], off, 64);
            }
        const int qa = qB_ + quad * 4, qbb = qa + 16;
#pragma unroll
        for (int j = 0; j < 4; j++) {
            const int d = j * 16 + col;
#pragma unroll
            for (int r = 0; r < 4; r++) {
                aout[((size_t)(b * Tc + qa + r)) * Cc + h * 64 + d] =
                    __float2bfloat16(oa[j][r] / la[r]);
                aout[((size_t)(b * Tc + qbb + r)) * Cc + h * 64 + d] =
                    __float2bfloat16(ob[j][r] / lb[r]);
            }
        }
    };

    if (wave < 4) stageA(0, 0);

    for (int i = 0; i < 17; i++) {
        __syncthreads();                      // step-i buffers staged
        // --- prefetch step i+1 ---
        if (i < 16) {
            if (wave < 4) stageA(i + 1, (i + 1) & 1);
            else if (i + 1 >= lightEnd) stageB(i + 16 - 2 * p, (i + 1) & 1);
        }
        // --- B-group transition: store light output, switch to heavy ---
        if (wave >= 4 && i == lightEnd) {
            outStore(qB);
#pragma unroll
            for (int j = 0; j < 4; j++) {
                oa[j] = floatx4{0.f, 0.f, 0.f, 0.f};
                ob[j] = floatx4{0.f, 0.f, 0.f, 0.f};
            }
#pragma unroll
            for (int r = 0; r < 4; r++) { la[r] = 0.f; lb[r] = 0.f; }
            qB = H * 128 + w3 * 32;
            qtw = (qB + 31) >> 6;
            q0a = qB + quad * 4;
            q0b = q0a + 16;
            const int qrA = qB + col, qrB2 = qrA + 16;
            qfa[0] = load8(qp + (size_t)qrA * Dc + quad * 8);
            qfa[1] = load8(qp + (size_t)qrA * Dc + 32 + quad * 8);
            qfb[0] = load8(qp + (size_t)qrB2 * Dc + quad * 8);
            qfb[1] = load8(qp + (size_t)qrB2 * Dc + 32 + quad * 8);
        }
        // --- compute ---
        if (wave < 4) {
            computeTile(kA + (i & 1) * 4096, vA + (i & 1) * 4096, i * 64);
        } else if (i < lightEnd) {
            if (i <= qtw)
                computeTile(kA + (i & 1) * 4096, vA + (i & 1) * 4096, i * 64);
        } else {
            const int kt = i + 15 - 2 * p;
            if (kt <= qtw)
                computeTile(kB + (i & 1) * 4096, vB + (i & 1) * 4096, kt * 64);
        }
        __syncthreads();                      // done reading step-i buffers
    }

    // --- combine heavy partials: B waves -> LDS -> A waves add ---
    if (wave >= 4) {
        float* c = comb + (size_t)(wave - 4) * 2560;
#pragma unroll
        for (int j = 0; j < 4; j++)
#pragma unroll
            for (int r = 0; r < 4; r++) {
                c[(j * 4 + r) * 64 + lane] = oa[j][r];
                c[(16 + j * 4 + r) * 64 + lane] = ob[j][r];
            }
#pragma unroll
        for (int r = 0; r < 4; r++) {
            c[(32 + r) * 64 + lane] = la[r];
            c[(36 + r) * 64 + lane] = lb[r];
        }
    }
    __syncthreads();
    if (wave < 4) {
        float* c = comb + (size_t)wave * 2560;
#pragma unroll
        for (int j = 0; j < 4; j++)
#pragma unroll
            for (int r = 0; r < 4; r++) {
                oa[j][r] += c[(j * 4 + r) * 64 + lane];
                ob[j][r] += c[(16 + j * 4 + r) * 64 + lane];
            }
#pragma unroll
        for (int r = 0; r < 4; r++) {
            la[r] += c[(32 + r) * 64 + lane];
            lb[r] += c[(36 + r) * 64 + lane];
        }
        outStore(qB);
    }
}

// ======== Fallback f32-staging GEMMs (used only if ws too small) ============
__global__ __launch_bounds__(256) void gemm_qkv(
    const float* __restrict__ A,
    const float* __restrict__ W,
    __hip_bfloat16* __restrict__ qkv) {
    __shared__ float As[128 * 32];
    __shared__ float Bs[128 * 32];
    const int K = Cc;
    const int lane = threadIdx.x & 63;
    const int wave = threadIdx.x >> 6;
    const int waveM = wave >> 1, waveN = wave & 1;
    const int mBase = blockIdx.x * 128;
    const int nBase = blockIdx.y * 128;
    const int idx16 = lane & 15;
    const int quad = lane >> 4;
    const int ldRow = lane >> 3;
    const int ldPos = lane & 7;

    floatx4 acc[4][4] = {};

    for (int k0 = 0; k0 < K; k0 += 32) {
        __syncthreads();
#pragma unroll
        for (int s = 0; s < 4; s++) {
            const int r0 = wave * 32 + s * 8;
            const int row = r0 + ldRow;
            const int cg = ldPos ^ (row & 7);
            gl2lds16(A + (size_t)(mBase + row) * K + k0 + cg * 4, &As[r0 * 32]);
            gl2lds16(W + (size_t)(nBase + row) * K + k0 + cg * 4, &Bs[r0 * 32]);
        }
        __syncthreads();

        bf16x8 af[4], bfr[4];
#pragma unroll
        for (int i = 0; i < 4; i++) {
            const int rr = waveM * 64 + i * 16 + idx16;
            const floatx4 a0 = *(const floatx4*)&As[rr * 32 + (((quad * 2) ^ (rr & 7)) * 4)];
            const floatx4 a1 = *(const floatx4*)&As[rr * 32 + (((quad * 2 + 1) ^ (rr & 7)) * 4)];
            af[i] = pack8(a0, a1);
        }
#pragma unroll
        for (int j = 0; j < 4; j++) {
            const int rr = waveN * 64 + j * 16 + idx16;
            const floatx4 b0 = *(const floatx4*)&Bs[rr * 32 + (((quad * 2) ^ (rr & 7)) * 4)];
            const floatx4 b1 = *(const floatx4*)&Bs[rr * 32 + (((quad * 2 + 1) ^ (rr & 7)) * 4)];
            bfr[j] = pack8(b0, b1);
        }
#pragma unroll
        for (int i = 0; i < 4; i++)
#pragma unroll
            for (int j = 0; j < 4; j++)
                acc[i][j] = MFMA16(af[i], bfr[j], acc[i][j]);
    }

#pragma unroll
    for (int i = 0; i < 4; i++) {
#pragma unroll
        for (int j = 0; j < 4; j++) {
            const int n = nBase + waveN * 64 + j * 16 + idx16;
            const int part = n >> 10;
            const int rem = n & 1023;
            const int h = rem >> 6, d = rem & 63;
#pragma unroll
            for (int r = 0; r < 4; r++) {
                const int m = mBase + waveM * 64 + i * 16 + quad * 4 + r;
                const int bb = m >> 11, t = m & 2047;
                const size_t o = (size_t)part * QKV_STRIDE +
                                 (((size_t)(bb * Hc + h)) * Tc + t) * Dc + d;
                qkv[o] = __float2bfloat16(acc[i][j][r]);
            }
        }
    }
}

__global__ __launch_bounds__(256) void gemm_proj(
    const __hip_bfloat16* __restrict__ A,
    const float* __restrict__ W,
    float* __restrict__ out) {
    __shared__ __hip_bfloat16 As16[128 * 32];
    __shared__ float Ws[64 * 32];
    const int K = Cc;
    const int lane = threadIdx.x & 63;
    const int wave = threadIdx.x >> 6;
    const int waveM = wave >> 1, waveN = wave & 1;
    const int mBase = blockIdx.x * 128;
    const int nBase = blockIdx.y * 64;
    const int idx16 = lane & 15;
    const int quad = lane >> 4;
    const int aRow = lane >> 2, aPos = lane & 3;
    const int wRow = lane >> 3, wPos = lane & 7;

    floatx4 acc[4][2] = {};

    for (int k0 = 0; k0 < K; k0 += 32) {
        __syncthreads();
#pragma unroll
        for (int s = 0; s < 2; s++) {
            {
                const int r0 = wave * 32 + s * 16;
                const int row = r0 + aRow;
                const int cg = aPos ^ (row & 3);
                gl2lds16(A + (size_t)(mBase + row) * K + k0 + cg * 8, &As16[r0 * 32]);
            }
            {
                const int r0 = wave * 16 + s * 8;
                const int row = r0 + wRow;
                const int cg = wPos ^ (row & 7);
                gl2lds16(W + (size_t)(nBase + row) * K + k0 + cg * 4, &Ws[r0 * 32]);
            }
        }
        __syncthreads();

        bf16x8 af[4], bfr[2];
#pragma unroll
        for (int i = 0; i < 4; i++) {
            const int rr = waveM * 64 + i * 16 + idx16;
            af[i] = *(const bf16x8*)&As16[rr * 32 + ((quad ^ (rr & 3)) * 8)];
        }
#pragma unroll
        for (int j = 0; j < 2; j++) {
            const int rr = waveN * 32 + j * 16 + idx16;
            const floatx4 b0 = *(const floatx4*)&Ws[rr * 32 + (((quad * 2) ^ (rr & 7)) * 4)];
            const floatx4 b1 = *(const floatx4*)&Ws[rr * 32 + (((quad * 2 + 1) ^ (rr & 7)) * 4)];
            bfr[j] = pack8(b0, b1);
        }
#pragma unroll
        for (int i = 0; i < 4; i++)
#pragma unroll
            for (int j = 0; j < 2; j++)
                acc[i][j] = MFMA16(af[i], bfr[j], acc[i][j]);
    }

#pragma unroll
    for (int i = 0; i < 4; i++) {
#pragma unroll
        for (int j = 0; j < 2; j++) {
            const int n = nBase + waveN * 32 + j * 16 + idx16;
#pragma unroll
            for (int r = 0; r < 4; r++) {
                const int m = mBase + waveM * 64 + i * 16 + quad * 4 + r;
                out[(size_t)m * Cc + n] = acc[i][j][r];
            }
        }
    }
}

extern "C" void kernel_launch(void* const* d_in, const int* in_sizes, int n_in,
                              void* d_out, int out_size, void* d_ws, size_t ws_size,
                              hipStream_t stream) {
    const float* x = nullptr;
    const float* w_qkv = nullptr;
    const float* w_proj = nullptr;
    for (int i = 0; i < n_in; i++) {
        if (in_sizes[i] == 4194304) x = (const float*)d_in[i];
        else if (in_sizes[i] == 3145728) w_qkv = (const float*)d_in[i];
        else if (in_sizes[i] == 1048576) w_proj = (const float*)d_in[i];
    }
    float* out = (float*)d_out;

    __hip_bfloat16* qkv = (__hip_bfloat16*)d_ws;        // q[4M] k[4M] v[4M]
    __hip_bfloat16* vbuf = qkv + 2 * QKV_STRIDE;        // v slot; becomes ao
    __hip_bfloat16* vt = qkv + 3 * QKV_STRIDE;          // 4M elems
    __hip_bfloat16* ao = vbuf;                          // attn out over dead v

    // bf16-input staging region after qkv+vt (8*QKV_STRIDE bytes = 32MB off)
    const size_t CVT_OFF = 8 * QKV_STRIDE;              // bytes
    const size_t NEED = CVT_OFF + (4194304 + 3145728) * sizeof(__hip_bfloat16);

    if (ws_size >= NEED) {
        __hip_bfloat16* xb = (__hip_bfloat16*)((char*)d_ws + CVT_OFF); // 8MB
        __hip_bfloat16* wbq = xb + 4194304;                            // 6MB
        __hip_bfloat16* wbp = qkv;    // q region, dead after attn

        cvt_bf16<<<dim3(4194304 / 8 / 256), 256, 0, stream>>>(x, xb, 4194304 / 8);
        cvt_bf16<<<dim3(3145728 / 8 / 256), 256, 0, stream>>>(w_qkv, wbq, 3145728 / 8);
        gemm_qkv_bf16<<<dim3(4096 / 128, 3072 / 128), 256, 0, stream>>>(xb, wbq, qkv);
        transpose_v<<<dim3(Tc / 64, Hc, Bc), 256, 0, stream>>>(vbuf, vt);
        attn_fold<<<dim3(8, Hc, Bc), 512, 0, stream>>>(qkv, vt, ao);
        cvt_bf16<<<dim3(1048576 / 8 / 256), 256, 0, stream>>>(w_proj, wbp, 1048576 / 8);
        gemm_proj_bf16<<<dim3(4096 / 128, 1024 / 64), 256, 0, stream>>>(ao, wbp, out);
    } else {
        gemm_qkv<<<dim3(4096 / 128, 3072 / 128), 256, 0, stream>>>(x, w_qkv, qkv);
        transpose_v<<<dim3(Tc / 64, Hc, Bc), 256, 0, stream>>>(vbuf, vt);
        attn_fold<<<dim3(8, Hc, Bc), 512, 0, stream>>>(qkv, vt, ao);
        gemm_proj<<<dim3(4096 / 128, 1024 / 64), 256, 0, stream>>>(ao, w_proj, out);
    }
}